// Round 8
// baseline (366.630 us; speedup 1.0000x reference)
//
#include <hip/hip_runtime.h>
#include <hip/hip_bf16.h>
#include <stdint.h>

// ---------------------------------------------------------------------------
// TransformerBlock fused forward for MI355X (gfx950).
// Shapes (fixed): B=8 TQ=512 TK=2048 D=1024 H=16 HD=64 NE=4 HID=32 NA=512.
//
// Round 8 (gemm_kv only; rest frozen):
//  * 3-deep staged pipeline w/ counted vmcnt: s_waitcnt vmcnt(6) + raw
//    s_barrier keeps 6 loads in flight ACROSS the barrier (2-phase drain
//    was the measured 60% stall; m233 regime).
//  * T2 bank swizzle on frag reads (chunk ^= (row^row>>2)&3, both-sides):
//    the 6.68M bank conflicts are the mainloop ds_read_b128s (8-way).
// ---------------------------------------------------------------------------

#define B_   8
#define TQ_  512
#define TK_  2048
#define D_   1024
#define H_   16
#define HD_  64
#define NE_  4
#define HID_ 32
#define EPSF 1e-6f
#define LOG2E 1.44269504f

typedef __bf16 bf16_t;
typedef __bf16 bf16x8 __attribute__((ext_vector_type(8)));
typedef __bf16 bf16x4 __attribute__((ext_vector_type(4)));
typedef float  f32x4  __attribute__((ext_vector_type(4)));

typedef __attribute__((address_space(1))) void gvoid_t;
typedef __attribute__((address_space(3))) void lvoid_t;

__device__ __forceinline__ void gld_lds16(const void* g, void* l) {
  __builtin_amdgcn_global_load_lds((gvoid_t*)g, (lvoid_t*)l, 16, 0, 0);
}

// ---------------------------------------------------------------------------
// Batched 1024x1024 fp32 -> bf16 transpose (Wq,Wk,Wv,Wo in one launch).
// ---------------------------------------------------------------------------
struct TP4 { const float* in[4]; bf16_t* out[4]; };

__global__ void transpose_conv4_kernel(TP4 p) {
  __shared__ float tile[32][33];
  const int bz = blockIdx.z;
  const float* in = p.in[bz];
  bf16_t* out = p.out[bz];
  const int rb = blockIdx.y * 32, cb = blockIdx.x * 32;
  const int txi = threadIdx.x, tyi = threadIdx.y;
#pragma unroll
  for (int i = 0; i < 32; i += 8)
    tile[tyi + i][txi] = in[(size_t)(rb + tyi + i) * D_ + cb + txi];
  __syncthreads();
#pragma unroll
  for (int i = 0; i < 32; i += 8)
    out[(size_t)(cb + tyi + i) * D_ + rb + txi] = (bf16_t)tile[txi][tyi + i];
}

// Generic small transpose (W1/W2).
__global__ void transpose_conv_kernel(const float* __restrict__ in, bf16_t* __restrict__ out,
                                      int R, int C, int in_bstride,
                                      int out_rstride, int ob_row, int ob_col) {
  __shared__ float tile[32][33];
  const int bz = blockIdx.z;
  const int rb = blockIdx.y * 32, cb = blockIdx.x * 32;
  const int txi = threadIdx.x, tyi = threadIdx.y;
  const float* inp = in + (size_t)bz * in_bstride;
#pragma unroll
  for (int i = 0; i < 32; i += 8) {
    const int r = rb + tyi + i, c = cb + txi;
    if (r < R && c < C) tile[tyi + i][txi] = inp[(size_t)r * C + c];
  }
  __syncthreads();
#pragma unroll
  for (int i = 0; i < 32; i += 8) {
    const int orow = cb + tyi + i;
    const int ocol = rb + txi;
    if (orow < C && ocol < R)
      out[(size_t)(orow + bz * ob_row) * out_rstride + bz * ob_col + ocol] =
          (bf16_t)tile[txi][tyi + i];
  }
}

__device__ __forceinline__ float block_rsum(float v, float* red) {
  v += __shfl_xor(v, 1);  v += __shfl_xor(v, 2);  v += __shfl_xor(v, 4);
  v += __shfl_xor(v, 8);  v += __shfl_xor(v, 16); v += __shfl_xor(v, 32);
  const int tid = threadIdx.x;
  if ((tid & 63) == 0) red[tid >> 6] = v;
  __syncthreads();
  return red[0] + red[1] + red[2] + red[3];
}

// ---------------------------------------------------------------------------
// RMSNorm of kv -> kvb (seg weights+bias), xn = rmsnorm(kv,fn_w), AND
// probs = softmax(x @ Wr + br)  (sim term is a softmax shift: dead).
// ---------------------------------------------------------------------------
__global__ __launch_bounds__(256)
void rms_kv_kernel(const float* __restrict__ kv, const float* __restrict__ kva_w,
                   const float* __restrict__ kvi_w, const float* __restrict__ fn_w,
                   const float* __restrict__ ab, const float* __restrict__ ib,
                   const int* __restrict__ n_act, const float* __restrict__ Wr,
                   const float* __restrict__ br,
                   bf16_t* __restrict__ kvb, bf16_t* __restrict__ xn,
                   float* __restrict__ probs) {
  __shared__ float red[4];
  __shared__ f32x4 pred[4];
  const int row = blockIdx.x;
  const int t = row & (TK_ - 1);
  const int tid = threadIdx.x;
  const float* src = kv + (size_t)row * D_;
  f32x4 v = ((const f32x4*)src)[tid];
  float ss = v[0]*v[0] + v[1]*v[1] + v[2]*v[2] + v[3]*v[3];
  ss = block_rsum(ss, red);
  const float rs = rsqrtf(ss * (1.0f / D_) + EPSF);
  const int Na = n_act[0];
  const float* wsel = (t < Na) ? kva_w : kvi_w;
  const float* bsel = (t < Na) ? ab : ib;
  const int d = tid * 4;
  f32x4 wv = *(const f32x4*)(wsel + d);
  f32x4 bv = *(const f32x4*)(bsel + d);
  f32x4 fv = *(const f32x4*)(fn_w + d);
  bf16x4 o0, o1;
  f32x4 p4 = {};
#pragma unroll
  for (int c = 0; c < 4; ++c) {
    const float xv = v[c] * rs;
    const float xf = xv * fv[c];
    o0[c] = (bf16_t)(xv * wv[c] + bv[c]);
    o1[c] = (bf16_t)xf;
    const f32x4 w4 = *(const f32x4*)&Wr[(d + c) * 4];
    p4 += w4 * xf;
  }
  *(bf16x4*)&kvb[(size_t)row * D_ + d] = o0;
  *(bf16x4*)&xn [(size_t)row * D_ + d] = o1;
#pragma unroll
  for (int m = 1; m <= 32; m <<= 1) {
    p4[0] += __shfl_xor(p4[0], m); p4[1] += __shfl_xor(p4[1], m);
    p4[2] += __shfl_xor(p4[2], m); p4[3] += __shfl_xor(p4[3], m);
  }
  if ((tid & 63) == 0) pred[tid >> 6] = p4;
  __syncthreads();
  if (tid == 0) {
    f32x4 s = pred[0] + pred[1] + pred[2] + pred[3];
    s[0] += br[0]; s[1] += br[1]; s[2] += br[2]; s[3] += br[3];
    const float mx = fmaxf(fmaxf(s[0], s[1]), fmaxf(s[2], s[3]));
    const float e0 = __expf(s[0] - mx), e1 = __expf(s[1] - mx);
    const float e2 = __expf(s[2] - mx), e3 = __expf(s[3] - mx);
    const float inv = 1.0f / (e0 + e1 + e2 + e3);
    f32x4 pr = { e0 * inv, e1 * inv, e2 * inv, e3 * inv };
    *(f32x4*)&probs[row * 4] = pr;
  }
}

__global__ __launch_bounds__(256)
void rms_q_kernel(const float* __restrict__ q, const float* __restrict__ qn_w,
                  bf16_t* __restrict__ qn) {
  __shared__ float red[4];
  const int row = blockIdx.x;
  const int tid = threadIdx.x;
  const float* src = q + (size_t)row * D_;
  f32x4 v = ((const f32x4*)src)[tid];
  float ss = v[0]*v[0] + v[1]*v[1] + v[2]*v[2] + v[3]*v[3];
  ss = block_rsum(ss, red);
  const float rs = rsqrtf(ss * (1.0f / D_) + EPSF);
  const int d = tid * 4;
  f32x4 wv = *(const f32x4*)(qn_w + d);
  bf16x4 o0;
#pragma unroll
  for (int c = 0; c < 4; ++c) o0[c] = (bf16_t)(v[c] * rs * wv[c]);
  *(bf16x4*)&qn[(size_t)row * D_ + d] = o0;
}

__device__ __forceinline__ int xcd_swz(int bx, int gx) {
  if ((gx & 7) == 0) { const int cpx = gx >> 3; return (bx & 7) * cpx + (bx >> 3); }
  return bx;
}

// ---------------------------------------------------------------------------
// FUSED K+V projection GEMM — 3-deep counted-vmcnt pipeline + T2 swizzle.
//   acc_k -> kbuf[tok][n];  acc_v -> vt[b][n][tok] (transposed epilogue).
// LDS: 3 buffers x (A 8KB | Bk 8KB | Bv 8KB) = 72 KB, 2 blocks/CU.
// Protocol per step t: vmcnt(6) [tile t's 6 loads done, tile t+1's stay in
// flight] -> s_barrier -> stage tile t+2 -> compute tile t.
// Swizzle: LDS[row][c] holds global chunk c ^ swz(row), swz=(r^(r>>2))&3;
// reads use chunk lgrp ^ swz -> 2-way banks (free).
// ---------------------------------------------------------------------------
__global__ __launch_bounds__(256)
void gemm_kv(const bf16_t* __restrict__ A, const bf16_t* __restrict__ Wk,
             const bf16_t* __restrict__ Wv, const float* __restrict__ bk,
             const float* __restrict__ bv, bf16_t* __restrict__ Kout,
             bf16_t* __restrict__ Vt) {
  __shared__ alignas(16) bf16_t lds[9 * 4096];   // As[3] | Bks[3] | Bvs[3]
  bf16_t* As  = lds;
  bf16_t* Bks = lds + 3 * 4096;
  bf16_t* Bvs = lds + 6 * 4096;
  const int K = D_;
  const int tid = threadIdx.x;
  const int lane = tid & 63;
  const int w = tid >> 6;
  const int wr = w >> 1, wc = w & 1;
  const int lane15 = lane & 15, lgrp = lane >> 4;

  // batch-per-XCD decomposition (1024 blocks)
  const int flat = blockIdx.x;
  const int xcd = flat & 7;
  const int local = flat >> 3;
  const int tg = local >> 3;
  const int yy = local & 7;
  const int m0 = (xcd * 16 + tg) * 128;
  const int n0 = yy * 128;

  f32x4 acc_k[4][4] = {};
  f32x4 acc_v[4][4] = {};

  // staging source with pre-swizzled chunk: thread (srow, c) loads chunk
  // c ^ swz(srow) so LDS slot (srow, c) = global chunk c ^ swz(srow).
  const int srow = tid >> 2;
  const int swzs = ((srow ^ (srow >> 2)) & 3) << 3;          // elem offset
  const int schunk = (((tid & 3) << 3) ^ swzs);
  const bf16_t* ga = A  + (size_t)(m0 + srow) * K + schunk;
  const bf16_t* gk = Wk + (size_t)(n0 + srow) * K + schunk;
  const bf16_t* gv = Wv + (size_t)(n0 + srow) * K + schunk;
  const size_t rstep = (size_t)64 * K;                       // row+64: same swz

  // frag read offsets (swizzled chunk)
  const int swzr = ((lane15 ^ (lane15 >> 2)) & 3) << 3;
  const int kbs  = (lgrp << 3) ^ swzr;
  const int ar   = ((wr * 64 + lane15) << 5) + kbs;
  const int br2  = ((wc * 64 + lane15) << 5) + kbs;

  auto STAGE = [&](int t, int bufi) {
    const int off = bufi * 4096;
    const int k0 = t * 32;
    gld_lds16(ga + k0,         &As [off + tid * 8]);
    gld_lds16(ga + k0 + rstep, &As [off + 2048 + tid * 8]);
    gld_lds16(gk + k0,         &Bks[off + tid * 8]);
    gld_lds16(gk + k0 + rstep, &Bks[off + 2048 + tid * 8]);
    gld_lds16(gv + k0,         &Bvs[off + tid * 8]);
    gld_lds16(gv + k0 + rstep, &Bvs[off + 2048 + tid * 8]);
  };

  STAGE(0, 0);
  STAGE(1, 1);

  const int NSTEP = K / 32;                                  // 32
  for (int t = 0; t < NSTEP; ++t) {
    if (t < NSTEP - 1) asm volatile("s_waitcnt vmcnt(6)" ::: "memory");
    else               asm volatile("s_waitcnt vmcnt(0)" ::: "memory");
    __builtin_amdgcn_s_barrier();
    if (t + 2 < NSTEP) STAGE(t + 2, (t + 2) % 3);
    const int off = (t % 3) * 4096;
    bf16x8 af[4], bkf[4], bvf[4];
#pragma unroll
    for (int i = 0; i < 4; ++i) af[i]  = *(const bf16x8*)&As [off + ar  + i * 512];
#pragma unroll
    for (int j = 0; j < 4; ++j) bkf[j] = *(const bf16x8*)&Bks[off + br2 + j * 512];
#pragma unroll
    for (int j = 0; j < 4; ++j) bvf[j] = *(const bf16x8*)&Bvs[off + br2 + j * 512];
    __builtin_amdgcn_s_setprio(1);
#pragma unroll
    for (int i = 0; i < 4; ++i)
#pragma unroll
      for (int j = 0; j < 4; ++j) {
        acc_k[i][j] = __builtin_amdgcn_mfma_f32_16x16x32_bf16(af[i], bkf[j], acc_k[i][j], 0, 0, 0);
        acc_v[i][j] = __builtin_amdgcn_mfma_f32_16x16x32_bf16(af[i], bvf[j], acc_v[i][j], 0, 0, 0);
      }
    __builtin_amdgcn_s_setprio(0);
  }

  // ---- K epilogue: Kout[tok][n] ----
  const int row0 = m0 + wr * 64 + (lgrp << 2);
  const int col0 = n0 + wc * 64 + lane15;
#pragma unroll
  for (int j = 0; j < 4; ++j) {
    const int cc = col0 + j * 16;
    const float bkv = bk[cc];
#pragma unroll
    for (int i = 0; i < 4; ++i) {
      const int rr = row0 + i * 16;
#pragma unroll
      for (int r = 0; r < 4; ++r)
        Kout[(size_t)(rr + r) * D_ + cc] = (bf16_t)(acc_k[i][j][r] + bkv);
    }
  }

  // ---- V epilogue: packed transpose via LDS, write vt[b][n][tok] ----
  __syncthreads();                       // mainloop LDS reads done; reuse lds
  bf16_t* vt_l = lds + w * 4608;         // 64 x 72 per wave (9216 B)
#pragma unroll
  for (int j = 0; j < 4; ++j) {
    const int nl = j * 16 + lane15;
    const float bvv = bv[n0 + wc * 64 + nl];
#pragma unroll
    for (int i = 0; i < 4; ++i) {
      bf16x4 pv;
#pragma unroll
      for (int r = 0; r < 4; ++r) pv[r] = (bf16_t)(acc_v[i][j][r] + bvv);
      *(bf16x4*)&vt_l[nl * 72 + i * 16 + lgrp * 4] = pv;   // 4 consecutive tok
    }
  }
  const int bidx2 = m0 >> 11;                          // batch
  const int tok0 = (m0 & (TK_ - 1)) + wr * 64;
  bf16_t* vbase = Vt + (size_t)bidx2 * D_ * TK_ + (size_t)(n0 + wc * 64) * TK_ + tok0;
#pragma unroll
  for (int it = 0; it < 8; ++it) {
    const int ln = (lane >> 3) + it * 8;
    const int tk = (lane & 7) * 8;
    const bf16x8 v8 = *(const bf16x8*)&vt_l[ln * 72 + tk];
    *(bf16x8*)&vbase[(size_t)ln * TK_ + tk] = v8;
  }
}

// ---------------------------------------------------------------------------
// Shared 128x128 GEMM mainloop (BK=32, dbuf) — used by moe GEMM.
// ---------------------------------------------------------------------------
__device__ __forceinline__ void gemm_loop_db(const bf16_t* __restrict__ ga,
                                             const bf16_t* __restrict__ gb,
                                             bf16_t* As, bf16_t* Bs, int K,
                                             size_t rstep, int ar, int br2,
                                             int tid, f32x4 acc[4][4]) {
  gld_lds16(ga,         &As[tid * 8]);
  gld_lds16(ga + rstep, &As[2048 + tid * 8]);
  gld_lds16(gb,         &Bs[tid * 8]);
  gld_lds16(gb + rstep, &Bs[2048 + tid * 8]);
  int buf = 0;
  for (int k0 = 0; k0 < K; k0 += 32) {
    __syncthreads();
    if (k0 + 32 < K) {
      const int nb = buf ^ 1;
      gld_lds16(ga + k0 + 32,         &As[nb * 4096 + tid * 8]);
      gld_lds16(ga + k0 + 32 + rstep, &As[nb * 4096 + 2048 + tid * 8]);
      gld_lds16(gb + k0 + 32,         &Bs[nb * 4096 + tid * 8]);
      gld_lds16(gb + k0 + 32 + rstep, &Bs[nb * 4096 + 2048 + tid * 8]);
    }
    bf16x8 af[4], bfr[4];
#pragma unroll
    for (int i = 0; i < 4; ++i) af[i]  = *(const bf16x8*)&As[buf * 4096 + ar  + i * 512];
#pragma unroll
    for (int j = 0; j < 4; ++j) bfr[j] = *(const bf16x8*)&Bs[buf * 4096 + br2 + j * 512];
#pragma unroll
    for (int i = 0; i < 4; ++i)
#pragma unroll
      for (int j = 0; j < 4; ++j)
        acc[i][j] = __builtin_amdgcn_mfma_f32_16x16x32_bf16(af[i], bfr[j], acc[i][j], 0, 0, 0);
    buf ^= 1;
  }
}

// ---------------------------------------------------------------------------
// Shared 64x128 GEMM mainloop (BK=32, dbuf) — small-M GEMMs.
// ---------------------------------------------------------------------------
__device__ __forceinline__ void gemm64_loop_db(const bf16_t* __restrict__ ga,
                                               const bf16_t* __restrict__ gb,
                                               bf16_t* As, bf16_t* Bs, int K,
                                               size_t rstep, int ar, int br2,
                                               int tid, f32x4 acc[2][4]) {
  gld_lds16(ga,         &As[tid * 8]);
  gld_lds16(gb,         &Bs[tid * 8]);
  gld_lds16(gb + rstep, &Bs[2048 + tid * 8]);
  int buf = 0;
  for (int k0 = 0; k0 < K; k0 += 32) {
    __syncthreads();
    if (k0 + 32 < K) {
      const int nb = buf ^ 1;
      gld_lds16(ga + k0 + 32,         &As[nb * 2048 + tid * 8]);
      gld_lds16(gb + k0 + 32,         &Bs[nb * 4096 + tid * 8]);
      gld_lds16(gb + k0 + 32 + rstep, &Bs[nb * 4096 + 2048 + tid * 8]);
    }
    bf16x8 af[2], bfr[4];
#pragma unroll
    for (int i = 0; i < 2; ++i) af[i]  = *(const bf16x8*)&As[buf * 2048 + ar  + i * 512];
#pragma unroll
    for (int j = 0; j < 4; ++j) bfr[j] = *(const bf16x8*)&Bs[buf * 4096 + br2 + j * 512];
#pragma unroll
    for (int i = 0; i < 2; ++i)
#pragma unroll
      for (int j = 0; j < 4; ++j)
        acc[i][j] = __builtin_amdgcn_mfma_f32_16x16x32_bf16(af[i], bfr[j], acc[i][j], 0, 0, 0);
    buf ^= 1;
  }
}

// ---------------------------------------------------------------------------
// 64x128 GEMM: C = A @ Wt^T (+bias[N]) — qp / proj.
// ---------------------------------------------------------------------------
template<int HAS_BIAS>
__global__ __launch_bounds__(256)
void gemm64_tn(const bf16_t* __restrict__ A, const bf16_t* __restrict__ Wt,
               const float* __restrict__ bias, bf16_t* __restrict__ C,
               int M, int N, int K) {
  __shared__ alignas(16) bf16_t As[2 * 64 * 32];
  __shared__ alignas(16) bf16_t Bs[2 * 128 * 32];
  const int tid = threadIdx.x;
  const int lane = tid & 63;
  const int w = tid >> 6;
  const int wr = w >> 1, wc = w & 1;
  const int m0 = xcd_swz(blockIdx.x, gridDim.x) * 64;
  const int n0 = blockIdx.y * 128;

  f32x4 acc[2][4] = {};
  const bf16_t* ga = A  + (size_t)(m0 + (tid >> 2)) * K + (tid & 3) * 8;
  const bf16_t* gb = Wt + (size_t)(n0 + (tid >> 2)) * K + (tid & 3) * 8;
  const int kb = (lane >> 4) * 8;
  const int ar  = ((wr * 32 + (lane & 15)) << 5) + kb;
  const int br2 = ((wc * 64 + (lane & 15)) << 5) + kb;

  gemm64_loop_db(ga, gb, As, Bs, K, (size_t)64 * K, ar, br2, tid, acc);

  const int row0 = m0 + wr * 32 + ((lane >> 4) << 2);
  const int col0 = n0 + wc * 64 + (lane & 15);
#pragma unroll
  for (int j = 0; j < 4; ++j) {
    const int cc = col0 + j * 16;
    const float bv = HAS_BIAS ? bias[cc] : 0.0f;
#pragma unroll
    for (int i = 0; i < 2; ++i) {
      const int rr = row0 + i * 16;
#pragma unroll
      for (int r = 0; r < 4; ++r)
        C[(size_t)(rr + r) * N + cc] = (bf16_t)(acc[i][j][r] + bv);
    }
  }
}

// ---------------------------------------------------------------------------
// 64x128-tile h-GEMM with fused bias + SiLU-gate + probs weighting -> a2.
// ---------------------------------------------------------------------------
__global__ __launch_bounds__(256)
void gemm64_h_act(const bf16_t* __restrict__ A, const bf16_t* __restrict__ Wt,
                  const float* __restrict__ bias, const float* __restrict__ probs,
                  bf16_t* __restrict__ a2) {
  __shared__ alignas(16) bf16_t As[2 * 64 * 32];
  __shared__ alignas(16) bf16_t Bs[2 * 128 * 32];
  const int K = D_;
  const int tid = threadIdx.x;
  const int lane = tid & 63;
  const int w = tid >> 6;
  const int wr = w >> 1, wc = w & 1;
  const int m0 = xcd_swz(blockIdx.x, gridDim.x) * 64;
  const int n0 = blockIdx.y * 128;

  f32x4 acc[2][4] = {};
  const bf16_t* ga = A  + (size_t)(m0 + (tid >> 2)) * K + (tid & 3) * 8;
  const bf16_t* gb = Wt + (size_t)(n0 + (tid >> 2)) * K + (tid & 3) * 8;
  const int kb = (lane >> 4) * 8;
  const int ar  = ((wr * 32 + (lane & 15)) << 5) + kb;
  const int br2 = ((wc * 64 + (lane & 15)) << 5) + kb;

  gemm64_loop_db(ga, gb, As, Bs, K, (size_t)64 * K, ar, br2, tid, acc);

  const int row0 = m0 + wr * 32 + ((lane >> 4) << 2);
  const int hbase = n0 + wc * 64 + (lane & 15);
  const int e = hbase >> 6;
#pragma unroll
  for (int j = 0; j < 2; ++j) {
    const int ch = hbase + j * 16;
    const float bx = bias[ch], bg = bias[ch + 32];
    const int ac = (ch & 63) + e * 32;
#pragma unroll
    for (int i = 0; i < 2; ++i) {
      const int rr = row0 + i * 16;
#pragma unroll
      for (int r = 0; r < 4; ++r) {
        const float xp = acc[i][j][r] + bx;
        const float g  = acc[i][j + 2][r] + bg;
        const float sg = 1.0f / (1.0f + __expf(-g));
        const float pr = probs[(size_t)(rr + r) * 4 + e];
        a2[(size_t)(rr + r) * 128 + ac] = (bf16_t)(pr * xp * g * sg);
      }
    }
  }
}

// ---------------------------------------------------------------------------
// moe-GEMM (K=128) with fused kv_new epilogue (fp32 out).
// ---------------------------------------------------------------------------
__global__ __launch_bounds__(256)
void gemm_moe_kvnew(const bf16_t* __restrict__ A, const bf16_t* __restrict__ Wt,
                    const float* __restrict__ kv, const float* __restrict__ probs,
                    const float* __restrict__ b2, const float* __restrict__ gate_ffn,
                    float* __restrict__ out) {
  __shared__ alignas(16) bf16_t As[2 * 128 * 32];
  __shared__ alignas(16) bf16_t Bs[2 * 128 * 32];
  const int K = 128, N = D_;
  const int tid = threadIdx.x;
  const int lane = tid & 63;
  const int w = tid >> 6;
  const int wr = w >> 1, wc = w & 1;
  const int m0 = xcd_swz(blockIdx.x, gridDim.x) * 128;
  const int n0 = blockIdx.y * 128;

  f32x4 acc[4][4] = {};
  const bf16_t* ga = A  + (size_t)(m0 + (tid >> 2)) * K + (tid & 3) * 8;
  const bf16_t* gb = Wt + (size_t)(n0 + (tid >> 2)) * K + (tid & 3) * 8;
  const int kb = (lane >> 4) * 8;
  const int ar  = ((wr * 64 + (lane & 15)) << 5) + kb;
  const int br2 = ((wc * 64 + (lane & 15)) << 5) + kb;

  gemm_loop_db(ga, gb, As, Bs, K, (size_t)64 * K, ar, br2, tid, acc);

  const float sgf = 1.0f / (1.0f + __expf(-gate_ffn[0]));
  const int row0 = m0 + wr * 64 + ((lane >> 4) << 2);
  const int col0 = n0 + wc * 64 + (lane & 15);
#pragma unroll
  for (int j = 0; j < 4; ++j) {
    const int cc = col0 + j * 16;
    const f32x4 b2v = { b2[0 * D_ + cc], b2[1 * D_ + cc], b2[2 * D_ + cc], b2[3 * D_ + cc] };
#pragma unroll
    for (int i = 0; i < 4; ++i) {
      const int rr = row0 + i * 16;
#pragma unroll
      for (int r = 0; r < 4; ++r) {
        const f32x4 pr = *(const f32x4*)&probs[(size_t)(rr + r) * 4];
        const float bsum = pr[0]*b2v[0] + pr[1]*b2v[1] + pr[2]*b2v[2] + pr[3]*b2v[3];
        out[(size_t)(rr + r) * N + cc] =
            kv[(size_t)(rr + r) * N + cc] + sgf * (acc[i][j][r] + bsum);
      }
    }
  }
}

// ---------------------------------------------------------------------------
// MFMA flash attention, two segments, no-max exp2 softmax, swapped QK^T.
// Block = 128 thr (2 waves) = (b, h, 64 q-rows); each wave 32 rows via two
// Q-frag sets. Grid 1024 -> 4 independent blocks/CU (LDS 40KB).
// ---------------------------------------------------------------------------
__global__ __launch_bounds__(128, 2)
void attn_mfma_kernel(const bf16_t* __restrict__ qp, const bf16_t* __restrict__ kb,
                      const bf16_t* __restrict__ vt, bf16_t* __restrict__ attno,
                      const float* __restrict__ log_temp, const int* __restrict__ n_act) {
  __shared__ alignas(16) bf16_t Ks[2][64 * 64];
  __shared__ alignas(16) bf16_t Vs[2][64 * 64];
  __shared__ alignas(16) bf16_t Ps[2][32 * 64];

  const int dd = blockIdx.x;
  const int xcd = dd & 7, within = dd >> 3;       // 8 q-tiles per (b,h) share XCD
  const int qt = within & 7, slot0 = within >> 3;
  const int bh = slot0 * 8 + xcd;
  const int b = bh >> 4, h = bh & 15;

  const int tid = threadIdx.x;
  const int lane = tid & 63;
  const int w = tid >> 6;                          // 0..1
  const int lane15 = lane & 15, lgrp = lane >> 4, l7 = lane & 7;
  const int Na = n_act[0];
  float temp = __expf(log_temp[0]);
  temp = fminf(fmaxf(temp, 0.1f), 10.0f);
  const float lsc = LOG2E / (64.0f * temp);
  const int rowbase = qt * 64 + w * 32;

  // Two Q B-frag sets, pre-scaled
  const bf16_t* qsrcA = qp + (size_t)(b * TQ_ + rowbase + lane15) * D_ + h * 64 + lgrp * 8;
  const bf16_t* qsrcB = qsrcA + (size_t)16 * D_;
  bf16x8 qfA0 = *(const bf16x8*)qsrcA;
  bf16x8 qfA1 = *(const bf16x8*)(qsrcA + 32);
  bf16x8 qfB0 = *(const bf16x8*)qsrcB;
  bf16x8 qfB1 = *(const bf16x8*)(qsrcB + 32);
#pragma unroll
  for (int j = 0; j < 8; ++j) {
    qfA0[j] = (bf16_t)((float)qfA0[j] * lsc);
    qfA1[j] = (bf16_t)((float)qfA1[j] * lsc);
    qfB0[j] = (bf16_t)((float)qfB0[j] * lsc);
    qfB1[j] = (bf16_t)((float)qfB1[j] * lsc);
  }

  // staging: 128 thr x 16B = 2KB = 16 rows/issue; 4 issues per 64x64 tile.
  const int srow = tid >> 3;                       // 0..15
  const int schunk = (tid & 7) ^ (srow & 7);       // (srow+16k)&7 == srow&7
  const bf16_t* ksrc = kb + (size_t)(b * TK_ + srow) * D_ + h * 64 + schunk * 8;
  const bf16_t* vsrc = vt + ((size_t)(b * 16 + h) * 64 + srow) * TK_ + schunk * 8;

  f32x4 oA[4] = {}, oB[4] = {}, outA[4] = {}, outB[4] = {};
  float laccA = 0.f, laccB = 0.f;

  const float inv_sa = rsqrtf((float)(Na > 1 ? Na : 1));
  const int Ni = TK_ - Na;
  const float inv_si = rsqrtf((float)(Ni > 1 ? Ni : 1));

#pragma unroll
  for (int r = 0; r < 4; ++r) {
    gld_lds16(ksrc + (size_t)r * 16 * D_, &Ks[0][r * 1024 + tid * 8]);
    gld_lds16(vsrc + (size_t)r * 16 * TK_, &Vs[0][r * 1024 + tid * 8]);
  }

  for (int t = 0; t < TK_ / 64; ++t) {
    const int cur = t & 1;
    __syncthreads();
    if (t + 1 < TK_ / 64) {
      const int nb = cur ^ 1;
      const bf16_t* kN = ksrc + (size_t)(t + 1) * 64 * D_;
      const bf16_t* vN = vsrc + (size_t)(t + 1) * 64;
#pragma unroll
      for (int r = 0; r < 4; ++r) {
        gld_lds16(kN + (size_t)r * 16 * D_, &Ks[nb][r * 1024 + tid * 8]);
        gld_lds16(vN + (size_t)r * 16 * TK_, &Vs[nb][r * 1024 + tid * 8]);
      }
    }

    // ---- S^T = K @ Q for both sets (K frags shared) ----
    f32x4 sA[4], sB[4];
    __builtin_amdgcn_s_setprio(1);
#pragma unroll
    for (int cf = 0; cf < 4; ++cf) {
      const int krow = (cf * 16 + lane15) * 64;
      const bf16x8 kf0 = *(const bf16x8*)&Ks[cur][krow + ((lgrp ^ l7) << 3)];
      const bf16x8 kf1 = *(const bf16x8*)&Ks[cur][krow + (((lgrp + 4) ^ l7) << 3)];
      f32x4 s = {};
      s = __builtin_amdgcn_mfma_f32_16x16x32_bf16(kf0, qfA0, s, 0, 0, 0);
      s = __builtin_amdgcn_mfma_f32_16x16x32_bf16(kf1, qfA1, s, 0, 0, 0);
      sA[cf] = s;
      f32x4 s2 = {};
      s2 = __builtin_amdgcn_mfma_f32_16x16x32_bf16(kf0, qfB0, s2, 0, 0, 0);
      s2 = __builtin_amdgcn_mfma_f32_16x16x32_bf16(kf1, qfB1, s2, 0, 0, 0);
      sB[cf] = s2;
    }
    __builtin_amdgcn_s_setprio(0);

    // ---- p = exp2(s); lane-local l; packed bf16x4 P stores ----
#pragma unroll
    for (int cf = 0; cf < 4; ++cf) {
      const int c = cf * 2 + (lgrp >> 1);
      const int pcol = ((c ^ l7) << 3) + (lgrp & 1) * 4;
      f32x4 pA, pB;
#pragma unroll
      for (int r = 0; r < 4; ++r) pA[r] = exp2f(sA[cf][r]);
#pragma unroll
      for (int r = 0; r < 4; ++r) pB[r] = exp2f(sB[cf][r]);
      laccA += (pA[0] + pA[1]) + (pA[2] + pA[3]);
      laccB += (pB[0] + pB[1]) + (pB[2] + pB[3]);
      bf16x4 pvA, pvB;
#pragma unroll
      for (int r = 0; r < 4; ++r) { pvA[r] = (bf16_t)pA[r]; pvB[r] = (bf16_t)pB[r]; }
      *(bf16x4*)&Ps[w][lane15 * 64 + pcol]        = pvA;
      *(bf16x4*)&Ps[w][(16 + lane15) * 64 + pcol] = pvB;
    }

    // ---- O += P @ V for both sets (V frags shared) ----
    {
      const int prowA = lane15 * 64;
      const int prowB = (16 + lane15) * 64;
      const bf16x8 paA0 = *(const bf16x8*)&Ps[w][prowA + ((lgrp ^ l7) << 3)];
      const bf16x8 paA1 = *(const bf16x8*)&Ps[w][prowA + (((lgrp + 4) ^ l7) << 3)];
      const bf16x8 paB0 = *(const bf16x8*)&Ps[w][prowB + ((lgrp ^ l7) << 3)];
      const bf16x8 paB1 = *(const bf16x8*)&Ps[w][prowB + (((lgrp + 4) ^ l7) << 3)];
      __builtin_amdgcn_s_setprio(1);
#pragma unroll
      for (int df = 0; df < 4; ++df) {
        const int vrow = (df * 16 + lane15) * 64;
        const bf16x8 vf0 = *(const bf16x8*)&Vs[cur][vrow + ((lgrp ^ l7) << 3)];
        const bf16x8 vf1 = *(const bf16x8*)&Vs[cur][vrow + (((lgrp + 4) ^ l7) << 3)];
        oA[df] = __builtin_amdgcn_mfma_f32_16x16x32_bf16(paA0, vf0, oA[df], 0, 0, 0);
        oA[df] = __builtin_amdgcn_mfma_f32_16x16x32_bf16(paA1, vf1, oA[df], 0, 0, 0);
        oB[df] = __builtin_amdgcn_mfma_f32_16x16x32_bf16(paB0, vf0, oB[df], 0, 0, 0);
        oB[df] = __builtin_amdgcn_mfma_f32_16x16x32_bf16(paB1, vf1, oB[df], 0, 0, 0);
      }
      __builtin_amdgcn_s_setprio(0);
    }

    // ---- segment finalize ----
    const bool endA = ((t + 1) * 64 == Na);
    const bool endI = (t == TK_ / 64 - 1);
    if (endA || endI) {
      float lA = laccA, lB = laccB;
      lA += __shfl_xor(lA, 16); lA += __shfl_xor(lA, 32);
      lB += __shfl_xor(lB, 16); lB += __shfl_xor(lB, 32);
      const float ssc = endA ? inv_sa : -inv_si;
      f32x4 ivA, ivB;
#pragma unroll
      for (int r = 0; r < 4; ++r) {
        ivA[r] = ssc / __shfl(lA, lgrp * 4 + r);
        ivB[r] = ssc / __shfl(lB, lgrp * 4 + r);
      }
#pragma unroll
      for (int df = 0; df < 4; ++df) {
        outA[df] += oA[df] * ivA; oA[df] = (f32x4){};
        outB[df] += oB[df] * ivB; oB[df] = (f32x4){};
      }
      laccA = 0.f; laccB = 0.f;
    }
  }

#pragma unroll
  for (int df = 0; df < 4; ++df)
#pragma unroll
    for (int r = 0; r < 4; ++r) {
      const size_t ro = (size_t)(b * TQ_ + rowbase + lgrp * 4 + r) * D_ + h * 64 + df * 16 + lane15;
      attno[ro]           = (bf16_t)outA[df][r];
      attno[ro + 16 * D_] = (bf16_t)outB[df][r];
    }
}

// ---------------------------------------------------------------------------
// delta = rmsnorm(proj, dn_w); q_new = q + sigmoid(gate_attn)*delta (fp32 out)
// ---------------------------------------------------------------------------
__global__ __launch_bounds__(256)
void delta_qnew_kernel(const bf16_t* __restrict__ proj, const float* __restrict__ dn_w,
                       const float* __restrict__ q, const float* __restrict__ gate_attn,
                       float* __restrict__ qnew) {
  __shared__ float red[4];
  const int row = blockIdx.x;
  const int tid = threadIdx.x;
  bf16x4 pv = *(const bf16x4*)(proj + (size_t)row * D_ + tid * 4);
  f32x4 v;
#pragma unroll
  for (int c = 0; c < 4; ++c) v[c] = (float)pv[c];
  float ss = v[0]*v[0] + v[1]*v[1] + v[2]*v[2] + v[3]*v[3];
  ss = block_rsum(ss, red);
  const float rs = rsqrtf(ss * (1.0f / D_) + EPSF);
  const float sga = 1.0f / (1.0f + __expf(-gate_attn[0]));
  const int d = tid * 4;
  f32x4 wv = *(const f32x4*)(dn_w + d);
  f32x4 qv = *(const f32x4*)(q + (size_t)row * D_ + d);
  f32x4 out;
#pragma unroll
  for (int c = 0; c < 4; ++c) out[c] = qv[c] + sga * (v[c] * rs * wv[c]);
  *(f32x4*)&qnew[(size_t)row * D_ + d] = out;
}

// ---------------------------------------------------------------------------
extern "C" void kernel_launch(void* const* d_in, const int* in_sizes, int n_in,
                              void* d_out, int out_size, void* d_ws, size_t ws_size,
                              hipStream_t stream) {
  const float* q           = (const float*)d_in[0];
  const float* kv          = (const float*)d_in[1];
  const float* qn_w        = (const float*)d_in[2];
  const float* kva_w       = (const float*)d_in[3];
  const float* kvi_w       = (const float*)d_in[4];
  const float* dn_w        = (const float*)d_in[5];
  const float* fn_w        = (const float*)d_in[6];
  const float* Wq          = (const float*)d_in[7];
  const float* bq          = (const float*)d_in[8];
  const float* Wk          = (const float*)d_in[9];
  const float* bk          = (const float*)d_in[10];
  const float* Wv          = (const float*)d_in[11];
  const float* bv          = (const float*)d_in[12];
  const float* Wo          = (const float*)d_in[13];
  const float* bo          = (const float*)d_in[14];
  const float* active_bias = (const float*)d_in[15];
  const float* inactive_b  = (const float*)d_in[16];
  const float* log_temp    = (const float*)d_in[17];
  const float* gate_attn   = (const float*)d_in[18];
  const float* gate_ffn    = (const float*)d_in[19];
  const float* Wr          = (const float*)d_in[20];
  const float* br          = (const float*)d_in[21];
  const float* W1          = (const float*)d_in[22];
  const float* b1          = (const float*)d_in[23];
  const float* W2          = (const float*)d_in[24];
  const float* b2          = (const float*)d_in[25];
  const int*   n_act       = (const int*)d_in[27];

  char* ws = (char*)d_ws;
  size_t off = 0;
  auto alloc = [&](size_t bytes) -> char* {
    char* p = ws + off;
    off = (off + bytes + 255) & ~(size_t)255;
    return p;
  };

  bf16_t* wqT  = (bf16_t*)alloc((size_t)D_ * D_ * 2);
  bf16_t* wkT  = (bf16_t*)alloc((size_t)D_ * D_ * 2);
  bf16_t* wvT  = (bf16_t*)alloc((size_t)D_ * D_ * 2);
  bf16_t* woT  = (bf16_t*)alloc((size_t)D_ * D_ * 2);
  bf16_t* w1T  = (bf16_t*)alloc((size_t)256 * D_ * 2);
  bf16_t* w2T  = (bf16_t*)alloc((size_t)D_ * 128 * 2);
  bf16_t* kvb  = (bf16_t*)alloc((size_t)B_ * TK_ * D_ * 2);
  bf16_t* xn   = (bf16_t*)alloc((size_t)B_ * TK_ * D_ * 2);
  bf16_t* qn   = (bf16_t*)alloc((size_t)B_ * TQ_ * D_ * 2);
  bf16_t* qp   = (bf16_t*)alloc((size_t)B_ * TQ_ * D_ * 2);
  bf16_t* kbuf = (bf16_t*)alloc((size_t)B_ * TK_ * D_ * 2);
  bf16_t* vt   = (bf16_t*)alloc((size_t)B_ * D_ * TK_ * 2);
  float*  probs = (float*)alloc((size_t)B_ * TK_ * NE_ * 4);
  bf16_t* attno = qn;    // qn consumed by qp GEMM before attention writes
  bf16_t* proj  = qp;    // qp consumed by attention before proj GEMM writes
  bf16_t* a2buf = kbuf;  // kbuf consumed by attention before h-act writes
  (void)ws_size; (void)in_sizes; (void)n_in; (void)out_size;

  float* q_new_out  = (float*)d_out;
  float* kv_new_out = (float*)d_out + (size_t)B_ * TQ_ * D_;

  dim3 tb(32, 8);
  TP4 tp;
  tp.in[0] = Wq; tp.in[1] = Wk; tp.in[2] = Wv; tp.in[3] = Wo;
  tp.out[0] = wqT; tp.out[1] = wkT; tp.out[2] = wvT; tp.out[3] = woT;
  transpose_conv4_kernel<<<dim3(32, 32, 4), tb, 0, stream>>>(tp);
  transpose_conv_kernel<<<dim3(2, 32, 4), tb, 0, stream>>>(W1, w1T, D_, 64, D_ * 64, D_, 64, 0);
  transpose_conv_kernel<<<dim3(32, 1, 4), tb, 0, stream>>>(W2, w2T, 32, D_, 32 * D_, 128, 0, 32);

  rms_kv_kernel<<<B_ * TK_, 256, 0, stream>>>(kv, kva_w, kvi_w, fn_w, active_bias,
                                              inactive_b, n_act, Wr, br, kvb, xn, probs);
  rms_q_kernel<<<B_ * TQ_, 256, 0, stream>>>(q, qn_w, qn);

  gemm64_tn<1><<<dim3(B_ * TQ_ / 64, D_ / 128), 256, 0, stream>>>(qn, wqT, bq, qp, B_ * TQ_, D_, D_);
  // fused K + V(transposed) projections, 3-deep counted-vmcnt pipeline
  gemm_kv<<<B_ * TK_ / 128 * (D_ / 128), 256, 0, stream>>>(kvb, wkT, wvT, bk, bv, kbuf, vt);

  attn_mfma_kernel<<<B_ * H_ * (TQ_ / 64), 128, 0, stream>>>(qp, kbuf, vt, attno, log_temp, n_act);

  gemm64_tn<1><<<dim3(B_ * TQ_ / 64, D_ / 128), 256, 0, stream>>>(attno, woT, bo, proj, B_ * TQ_, D_, D_);
  delta_qnew_kernel<<<B_ * TQ_, 256, 0, stream>>>(proj, dn_w, q, gate_attn, q_new_out);

  gemm64_h_act<<<dim3(B_ * TK_ / 64, 2), 256, 0, stream>>>(xn, w1T, b1, probs, a2buf);
  gemm_moe_kvnew<<<dim3(B_ * TK_ / 128, D_ / 128), 256, 0, stream>>>(a2buf, w2T, kv, probs, b2,
                                                                     gate_ffn, kv_new_out);
}

// Round 9
// 351.957 us; speedup vs baseline: 1.0417x; 1.0417x over previous
//
#include <hip/hip_runtime.h>
#include <hip/hip_bf16.h>
#include <stdint.h>

// ---------------------------------------------------------------------------
// TransformerBlock fused forward for MI355X (gfx950).
// Shapes (fixed): B=8 TQ=512 TK=2048 D=1024 H=16 HD=64 NE=4 HID=32 NA=512.
//
// Round 9:
//  * gemm_kv: FRAG-ORDERED global layout for A (kvb, written by rms_kv) and
//    B (wk/wv, new transpose): [tile][s][half][frag][lane][8elem]. LDS layout
//    (= global order under global_load_lds) now makes every ds_read_b128 a
//    contiguous 1KB wave read -> zero bank conflicts (r6-r8's 6.68M was the
//    [row][k] 64B-row layout's intrinsic 8-way histogram — lane-XOR can't
//    fix a multiset). Loop reverted to r7 2-buffer (r8 pipeline regressed).
// ---------------------------------------------------------------------------

#define B_   8
#define TQ_  512
#define TK_  2048
#define D_   1024
#define H_   16
#define HD_  64
#define NE_  4
#define HID_ 32
#define EPSF 1e-6f
#define LOG2E 1.44269504f

typedef __bf16 bf16_t;
typedef __bf16 bf16x8 __attribute__((ext_vector_type(8)));
typedef __bf16 bf16x4 __attribute__((ext_vector_type(4)));
typedef float  f32x4  __attribute__((ext_vector_type(4)));

typedef __attribute__((address_space(1))) void gvoid_t;
typedef __attribute__((address_space(3))) void lvoid_t;

__device__ __forceinline__ void gld_lds16(const void* g, void* l) {
  __builtin_amdgcn_global_load_lds((gvoid_t*)g, (lvoid_t*)l, 16, 0, 0);
}

// ---------------------------------------------------------------------------
// Batched 1024x1024 fp32 -> bf16 transpose (Wq, Wo) to (N,K) row-major.
// ---------------------------------------------------------------------------
struct TP2 { const float* in[2]; bf16_t* out[2]; };

__global__ void transpose_conv2_kernel(TP2 p) {
  __shared__ float tile[32][33];
  const int bz = blockIdx.z;
  const float* in = p.in[bz];
  bf16_t* out = p.out[bz];
  const int rb = blockIdx.y * 32, cb = blockIdx.x * 32;
  const int txi = threadIdx.x, tyi = threadIdx.y;
#pragma unroll
  for (int i = 0; i < 32; i += 8)
    tile[tyi + i][txi] = in[(size_t)(rb + tyi + i) * D_ + cb + txi];
  __syncthreads();
#pragma unroll
  for (int i = 0; i < 32; i += 8)
    out[(size_t)(cb + tyi + i) * D_ + rb + txi] = (bf16_t)tile[txi][tyi + i];
}

// ---------------------------------------------------------------------------
// Frag-ordered weight transpose for Wk/Wv: W(k,n) ->
//   out[tile_n*131072 + s*4096 + hc*2048 + j*512 + (lg*16+l15)*8 + e]
// with n = col (output feature): hc=(n&127)>>6, j=(n&63)>>4, l15=n&15;
//      k: s=k>>5, lg=(k>>3)&3, e=k&7.
// ---------------------------------------------------------------------------
__global__ void transpose_fragorder_kernel(TP2 p) {
  __shared__ float tile[32][33];
  const float* in = p.in[blockIdx.z];
  bf16_t* out = p.out[blockIdx.z];
  const int kb0 = blockIdx.y * 32;
  const int nb0 = blockIdx.x * 32;
  const int tx = threadIdx.x, ty = threadIdx.y;
#pragma unroll
  for (int i = 0; i < 32; i += 8)
    tile[ty + i][tx] = in[(size_t)(kb0 + ty + i) * D_ + nb0 + tx];
  __syncthreads();
  const int t = ty * 32 + tx;          // 0..255
  const int n_l = t >> 3;              // 0..31
  const int k_l = (t & 7) * 4;         // 0,4,...,28
  const int n = nb0 + n_l;
  const int k = kb0 + k_l;
  const int tile_n = n >> 7, rn = n & 127, hc = rn >> 6, rr = rn & 63;
  const int j = rr >> 4, l15 = rr & 15;
  const int s = k >> 5, lg = (k >> 3) & 3, e = k & 7;
  bf16x4 o;
#pragma unroll
  for (int c = 0; c < 4; ++c) o[c] = (bf16_t)tile[k_l + c][n_l];
  *(bf16x4*)&out[(size_t)tile_n * 131072 + s * 4096 + hc * 2048 +
                 j * 512 + (lg * 16 + l15) * 8 + e] = o;
}

// Generic small transpose (W1/W2).
__global__ void transpose_conv_kernel(const float* __restrict__ in, bf16_t* __restrict__ out,
                                      int R, int C, int in_bstride,
                                      int out_rstride, int ob_row, int ob_col) {
  __shared__ float tile[32][33];
  const int bz = blockIdx.z;
  const int rb = blockIdx.y * 32, cb = blockIdx.x * 32;
  const int txi = threadIdx.x, tyi = threadIdx.y;
  const float* inp = in + (size_t)bz * in_bstride;
#pragma unroll
  for (int i = 0; i < 32; i += 8) {
    const int r = rb + tyi + i, c = cb + txi;
    if (r < R && c < C) tile[tyi + i][txi] = inp[(size_t)r * C + c];
  }
  __syncthreads();
#pragma unroll
  for (int i = 0; i < 32; i += 8) {
    const int orow = cb + tyi + i;
    const int ocol = rb + txi;
    if (orow < C && ocol < R)
      out[(size_t)(orow + bz * ob_row) * out_rstride + bz * ob_col + ocol] =
          (bf16_t)tile[txi][tyi + i];
  }
}

__device__ __forceinline__ float block_rsum(float v, float* red) {
  v += __shfl_xor(v, 1);  v += __shfl_xor(v, 2);  v += __shfl_xor(v, 4);
  v += __shfl_xor(v, 8);  v += __shfl_xor(v, 16); v += __shfl_xor(v, 32);
  const int tid = threadIdx.x;
  if ((tid & 63) == 0) red[tid >> 6] = v;
  __syncthreads();
  return red[0] + red[1] + red[2] + red[3];
}

// ---------------------------------------------------------------------------
// RMSNorm of kv -> kvb (seg weights+bias, FRAG-ORDERED for gemm_kv),
// xn = rmsnorm(kv,fn_w) (row-major), probs = softmax(x@Wr + br).
// ---------------------------------------------------------------------------
__global__ __launch_bounds__(256)
void rms_kv_kernel(const float* __restrict__ kv, const float* __restrict__ kva_w,
                   const float* __restrict__ kvi_w, const float* __restrict__ fn_w,
                   const float* __restrict__ ab, const float* __restrict__ ib,
                   const int* __restrict__ n_act, const float* __restrict__ Wr,
                   const float* __restrict__ br,
                   bf16_t* __restrict__ kvb, bf16_t* __restrict__ xn,
                   float* __restrict__ probs) {
  __shared__ float red[4];
  __shared__ f32x4 pred[4];
  const int row = blockIdx.x;
  const int t = row & (TK_ - 1);
  const int tid = threadIdx.x;
  const float* src = kv + (size_t)row * D_;
  f32x4 v = ((const f32x4*)src)[tid];
  float ss = v[0]*v[0] + v[1]*v[1] + v[2]*v[2] + v[3]*v[3];
  ss = block_rsum(ss, red);
  const float rs = rsqrtf(ss * (1.0f / D_) + EPSF);
  const int Na = n_act[0];
  const float* wsel = (t < Na) ? kva_w : kvi_w;
  const float* bsel = (t < Na) ? ab : ib;
  const int d = tid * 4;
  f32x4 wv = *(const f32x4*)(wsel + d);
  f32x4 bv = *(const f32x4*)(bsel + d);
  f32x4 fv = *(const f32x4*)(fn_w + d);
  bf16x4 o0, o1;
  f32x4 p4 = {};
#pragma unroll
  for (int c = 0; c < 4; ++c) {
    const float xv = v[c] * rs;
    const float xf = xv * fv[c];
    o0[c] = (bf16_t)(xv * wv[c] + bv[c]);
    o1[c] = (bf16_t)xf;
    const f32x4 w4 = *(const f32x4*)&Wr[(d + c) * 4];
    p4 += w4 * xf;
  }
  // kvb frag-ordered: row -> (tile_m, h, i, l15); d -> (s, lg, e)
  {
    const int rl = row & 127, hh = rl >> 6, rr2 = rl & 63;
    const int ii = rr2 >> 4, l15 = rr2 & 15;
    const int s2 = d >> 5, lg2 = (d >> 3) & 3, e2 = d & 7;
    *(bf16x4*)&kvb[(size_t)(row >> 7) * 131072 + s2 * 4096 + hh * 2048 +
                   ii * 512 + (lg2 * 16 + l15) * 8 + e2] = o0;
  }
  *(bf16x4*)&xn[(size_t)row * D_ + d] = o1;
#pragma unroll
  for (int m = 1; m <= 32; m <<= 1) {
    p4[0] += __shfl_xor(p4[0], m); p4[1] += __shfl_xor(p4[1], m);
    p4[2] += __shfl_xor(p4[2], m); p4[3] += __shfl_xor(p4[3], m);
  }
  if ((tid & 63) == 0) pred[tid >> 6] = p4;
  __syncthreads();
  if (tid == 0) {
    f32x4 s = pred[0] + pred[1] + pred[2] + pred[3];
    s[0] += br[0]; s[1] += br[1]; s[2] += br[2]; s[3] += br[3];
    const float mx = fmaxf(fmaxf(s[0], s[1]), fmaxf(s[2], s[3]));
    const float e0 = __expf(s[0] - mx), e1 = __expf(s[1] - mx);
    const float e2 = __expf(s[2] - mx), e3 = __expf(s[3] - mx);
    const float inv = 1.0f / (e0 + e1 + e2 + e3);
    f32x4 pr = { e0 * inv, e1 * inv, e2 * inv, e3 * inv };
    *(f32x4*)&probs[row * 4] = pr;
  }
}

__global__ __launch_bounds__(256)
void rms_q_kernel(const float* __restrict__ q, const float* __restrict__ qn_w,
                  bf16_t* __restrict__ qn) {
  __shared__ float red[4];
  const int row = blockIdx.x;
  const int tid = threadIdx.x;
  const float* src = q + (size_t)row * D_;
  f32x4 v = ((const f32x4*)src)[tid];
  float ss = v[0]*v[0] + v[1]*v[1] + v[2]*v[2] + v[3]*v[3];
  ss = block_rsum(ss, red);
  const float rs = rsqrtf(ss * (1.0f / D_) + EPSF);
  const int d = tid * 4;
  f32x4 wv = *(const f32x4*)(qn_w + d);
  bf16x4 o0;
#pragma unroll
  for (int c = 0; c < 4; ++c) o0[c] = (bf16_t)(v[c] * rs * wv[c]);
  *(bf16x4*)&qn[(size_t)row * D_ + d] = o0;
}

__device__ __forceinline__ int xcd_swz(int bx, int gx) {
  if ((gx & 7) == 0) { const int cpx = gx >> 3; return (bx & 7) * cpx + (bx >> 3); }
  return bx;
}

// ---------------------------------------------------------------------------
// FUSED K+V projection GEMM, frag-ordered inputs.
//   A: kvb frag-ordered [tile_m][s][h][i][lane][8]
//   B: wk/wv frag-ordered [tile_n][s][hc][j][lane][8]
// Staging is fully linear; frag reads are contiguous 1KB/wave (0 conflicts).
//   acc_k -> kbuf[tok][n];  acc_v -> vt[b][n][tok] (LDS-transposed epilogue).
// ---------------------------------------------------------------------------
__global__ __launch_bounds__(256)
void gemm_kv(const bf16_t* __restrict__ A, const bf16_t* __restrict__ Wk,
             const bf16_t* __restrict__ Wv, const float* __restrict__ bk,
             const float* __restrict__ bv, bf16_t* __restrict__ Kout,
             bf16_t* __restrict__ Vt) {
  __shared__ alignas(16) bf16_t lds[3 * 8192];   // As | Bks | Bvs (2 bufs each)
  bf16_t* As  = lds;
  bf16_t* Bks = lds + 8192;
  bf16_t* Bvs = lds + 16384;
  const int tid = threadIdx.x;
  const int lane = tid & 63;
  const int w = tid >> 6;
  const int wr = w >> 1, wc = w & 1;
  const int lane15 = lane & 15, lgrp = lane >> 4;

  // batch-per-XCD decomposition (1024 blocks)
  const int flat = blockIdx.x;
  const int xcd = flat & 7;
  const int local = flat >> 3;
  const int tg = local >> 3;
  const int yy = local & 7;
  const int m0 = (xcd * 16 + tg) * 128;
  const int n0 = yy * 128;

  f32x4 acc_k[4][4] = {};
  f32x4 acc_v[4][4] = {};

  const bf16_t* ga = A  + (size_t)(m0 >> 7) * 131072 + tid * 8;
  const bf16_t* gk = Wk + (size_t)(n0 >> 7) * 131072 + tid * 8;
  const bf16_t* gv = Wv + (size_t)(n0 >> 7) * 131072 + tid * 8;

  auto STAGE = [&](int s, int bufi) {
    const int off = bufi * 4096;
    const size_t so = (size_t)s * 4096;
    gld_lds16(ga + so,        &As [off + tid * 8]);
    gld_lds16(ga + so + 2048, &As [off + 2048 + tid * 8]);
    gld_lds16(gk + so,        &Bks[off + tid * 8]);
    gld_lds16(gk + so + 2048, &Bks[off + 2048 + tid * 8]);
    gld_lds16(gv + so,        &Bvs[off + tid * 8]);
    gld_lds16(gv + so + 2048, &Bvs[off + 2048 + tid * 8]);
  };

  STAGE(0, 0);
  int buf = 0;
  const int abase0 = wr * 2048 + lane * 8;
  const int bbase0 = wc * 2048 + lane * 8;
  for (int s = 0; s < 32; ++s) {
    __syncthreads();
    if (s + 1 < 32) STAGE(s + 1, buf ^ 1);
    const int off = buf * 4096;
    bf16x8 af[4], bkf[4], bvf[4];
#pragma unroll
    for (int i = 0; i < 4; ++i) af[i]  = *(const bf16x8*)&As [off + abase0 + i * 512];
#pragma unroll
    for (int j = 0; j < 4; ++j) bkf[j] = *(const bf16x8*)&Bks[off + bbase0 + j * 512];
#pragma unroll
    for (int j = 0; j < 4; ++j) bvf[j] = *(const bf16x8*)&Bvs[off + bbase0 + j * 512];
    __builtin_amdgcn_s_setprio(1);
#pragma unroll
    for (int i = 0; i < 4; ++i)
#pragma unroll
      for (int j = 0; j < 4; ++j) {
        acc_k[i][j] = __builtin_amdgcn_mfma_f32_16x16x32_bf16(af[i], bkf[j], acc_k[i][j], 0, 0, 0);
        acc_v[i][j] = __builtin_amdgcn_mfma_f32_16x16x32_bf16(af[i], bvf[j], acc_v[i][j], 0, 0, 0);
      }
    __builtin_amdgcn_s_setprio(0);
    buf ^= 1;
  }

  // ---- K epilogue: Kout[tok][n] ----
  const int row0 = m0 + wr * 64 + (lgrp << 2);
  const int col0 = n0 + wc * 64 + lane15;
#pragma unroll
  for (int j = 0; j < 4; ++j) {
    const int cc = col0 + j * 16;
    const float bkv = bk[cc];
#pragma unroll
    for (int i = 0; i < 4; ++i) {
      const int rr = row0 + i * 16;
#pragma unroll
      for (int r = 0; r < 4; ++r)
        Kout[(size_t)(rr + r) * D_ + cc] = (bf16_t)(acc_k[i][j][r] + bkv);
    }
  }

  // ---- V epilogue: packed transpose via LDS, write vt[b][n][tok] ----
  __syncthreads();                       // mainloop LDS reads done; reuse lds
  bf16_t* vt_l = lds + w * 4608;         // 64 x 72 per wave (9216 B)
#pragma unroll
  for (int j = 0; j < 4; ++j) {
    const int nl = j * 16 + lane15;
    const float bvv = bv[n0 + wc * 64 + nl];
#pragma unroll
    for (int i = 0; i < 4; ++i) {
      bf16x4 pv;
#pragma unroll
      for (int r = 0; r < 4; ++r) pv[r] = (bf16_t)(acc_v[i][j][r] + bvv);
      *(bf16x4*)&vt_l[nl * 72 + i * 16 + lgrp * 4] = pv;   // 4 consecutive tok
    }
  }
  const int bidx2 = m0 >> 11;                          // batch
  const int tok0 = (m0 & (TK_ - 1)) + wr * 64;
  bf16_t* vbase = Vt + (size_t)bidx2 * D_ * TK_ + (size_t)(n0 + wc * 64) * TK_ + tok0;
#pragma unroll
  for (int it = 0; it < 8; ++it) {
    const int ln = (lane >> 3) + it * 8;
    const int tk = (lane & 7) * 8;
    const bf16x8 v8 = *(const bf16x8*)&vt_l[ln * 72 + tk];
    *(bf16x8*)&vbase[(size_t)ln * TK_ + tk] = v8;
  }
}

// ---------------------------------------------------------------------------
// Shared 128x128 GEMM mainloop (BK=32, dbuf) — used by moe GEMM.
// ---------------------------------------------------------------------------
__device__ __forceinline__ void gemm_loop_db(const bf16_t* __restrict__ ga,
                                             const bf16_t* __restrict__ gb,
                                             bf16_t* As, bf16_t* Bs, int K,
                                             size_t rstep, int ar, int br2,
                                             int tid, f32x4 acc[4][4]) {
  gld_lds16(ga,         &As[tid * 8]);
  gld_lds16(ga + rstep, &As[2048 + tid * 8]);
  gld_lds16(gb,         &Bs[tid * 8]);
  gld_lds16(gb + rstep, &Bs[2048 + tid * 8]);
  int buf = 0;
  for (int k0 = 0; k0 < K; k0 += 32) {
    __syncthreads();
    if (k0 + 32 < K) {
      const int nb = buf ^ 1;
      gld_lds16(ga + k0 + 32,         &As[nb * 4096 + tid * 8]);
      gld_lds16(ga + k0 + 32 + rstep, &As[nb * 4096 + 2048 + tid * 8]);
      gld_lds16(gb + k0 + 32,         &Bs[nb * 4096 + tid * 8]);
      gld_lds16(gb + k0 + 32 + rstep, &Bs[nb * 4096 + 2048 + tid * 8]);
    }
    bf16x8 af[4], bfr[4];
#pragma unroll
    for (int i = 0; i < 4; ++i) af[i]  = *(const bf16x8*)&As[buf * 4096 + ar  + i * 512];
#pragma unroll
    for (int j = 0; j < 4; ++j) bfr[j] = *(const bf16x8*)&Bs[buf * 4096 + br2 + j * 512];
#pragma unroll
    for (int i = 0; i < 4; ++i)
#pragma unroll
      for (int j = 0; j < 4; ++j)
        acc[i][j] = __builtin_amdgcn_mfma_f32_16x16x32_bf16(af[i], bfr[j], acc[i][j], 0, 0, 0);
    buf ^= 1;
  }
}

// ---------------------------------------------------------------------------
// Shared 64x128 GEMM mainloop (BK=32, dbuf) — small-M GEMMs.
// ---------------------------------------------------------------------------
__device__ __forceinline__ void gemm64_loop_db(const bf16_t* __restrict__ ga,
                                               const bf16_t* __restrict__ gb,
                                               bf16_t* As, bf16_t* Bs, int K,
                                               size_t rstep, int ar, int br2,
                                               int tid, f32x4 acc[2][4]) {
  gld_lds16(ga,         &As[tid * 8]);
  gld_lds16(gb,         &Bs[tid * 8]);
  gld_lds16(gb + rstep, &Bs[2048 + tid * 8]);
  int buf = 0;
  for (int k0 = 0; k0 < K; k0 += 32) {
    __syncthreads();
    if (k0 + 32 < K) {
      const int nb = buf ^ 1;
      gld_lds16(ga + k0 + 32,         &As[nb * 2048 + tid * 8]);
      gld_lds16(gb + k0 + 32,         &Bs[nb * 4096 + tid * 8]);
      gld_lds16(gb + k0 + 32 + rstep, &Bs[nb * 4096 + 2048 + tid * 8]);
    }
    bf16x8 af[2], bfr[4];
#pragma unroll
    for (int i = 0; i < 2; ++i) af[i]  = *(const bf16x8*)&As[buf * 2048 + ar  + i * 512];
#pragma unroll
    for (int j = 0; j < 4; ++j) bfr[j] = *(const bf16x8*)&Bs[buf * 4096 + br2 + j * 512];
#pragma unroll
    for (int i = 0; i < 2; ++i)
#pragma unroll
      for (int j = 0; j < 4; ++j)
        acc[i][j] = __builtin_amdgcn_mfma_f32_16x16x32_bf16(af[i], bfr[j], acc[i][j], 0, 0, 0);
    buf ^= 1;
  }
}

// ---------------------------------------------------------------------------
// 64x128 GEMM: C = A @ Wt^T (+bias[N]) — qp / proj.
// ---------------------------------------------------------------------------
template<int HAS_BIAS>
__global__ __launch_bounds__(256)
void gemm64_tn(const bf16_t* __restrict__ A, const bf16_t* __restrict__ Wt,
               const float* __restrict__ bias, bf16_t* __restrict__ C,
               int M, int N, int K) {
  __shared__ alignas(16) bf16_t As[2 * 64 * 32];
  __shared__ alignas(16) bf16_t Bs[2 * 128 * 32];
  const int tid = threadIdx.x;
  const int lane = tid & 63;
  const int w = tid >> 6;
  const int wr = w >> 1, wc = w & 1;
  const int m0 = xcd_swz(blockIdx.x, gridDim.x) * 64;
  const int n0 = blockIdx.y * 128;

  f32x4 acc[2][4] = {};
  const bf16_t* ga = A  + (size_t)(m0 + (tid >> 2)) * K + (tid & 3) * 8;
  const bf16_t* gb = Wt + (size_t)(n0 + (tid >> 2)) * K + (tid & 3) * 8;
  const int kb = (lane >> 4) * 8;
  const int ar  = ((wr * 32 + (lane & 15)) << 5) + kb;
  const int br2 = ((wc * 64 + (lane & 15)) << 5) + kb;

  gemm64_loop_db(ga, gb, As, Bs, K, (size_t)64 * K, ar, br2, tid, acc);

  const int row0 = m0 + wr * 32 + ((lane >> 4) << 2);
  const int col0 = n0 + wc * 64 + (lane & 15);
#pragma unroll
  for (int j = 0; j < 4; ++j) {
    const int cc = col0 + j * 16;
    const float bv = HAS_BIAS ? bias[cc] : 0.0f;
#pragma unroll
    for (int i = 0; i < 2; ++i) {
      const int rr = row0 + i * 16;
#pragma unroll
      for (int r = 0; r < 4; ++r)
        C[(size_t)(rr + r) * N + cc] = (bf16_t)(acc[i][j][r] + bv);
    }
  }
}

// ---------------------------------------------------------------------------
// 64x128-tile h-GEMM with fused bias + SiLU-gate + probs weighting -> a2.
// ---------------------------------------------------------------------------
__global__ __launch_bounds__(256)
void gemm64_h_act(const bf16_t* __restrict__ A, const bf16_t* __restrict__ Wt,
                  const float* __restrict__ bias, const float* __restrict__ probs,
                  bf16_t* __restrict__ a2) {
  __shared__ alignas(16) bf16_t As[2 * 64 * 32];
  __shared__ alignas(16) bf16_t Bs[2 * 128 * 32];
  const int K = D_;
  const int tid = threadIdx.x;
  const int lane = tid & 63;
  const int w = tid >> 6;
  const int wr = w >> 1, wc = w & 1;
  const int m0 = xcd_swz(blockIdx.x, gridDim.x) * 64;
  const int n0 = blockIdx.y * 128;

  f32x4 acc[2][4] = {};
  const bf16_t* ga = A  + (size_t)(m0 + (tid >> 2)) * K + (tid & 3) * 8;
  const bf16_t* gb = Wt + (size_t)(n0 + (tid >> 2)) * K + (tid & 3) * 8;
  const int kb = (lane >> 4) * 8;
  const int ar  = ((wr * 32 + (lane & 15)) << 5) + kb;
  const int br2 = ((wc * 64 + (lane & 15)) << 5) + kb;

  gemm64_loop_db(ga, gb, As, Bs, K, (size_t)64 * K, ar, br2, tid, acc);

  const int row0 = m0 + wr * 32 + ((lane >> 4) << 2);
  const int hbase = n0 + wc * 64 + (lane & 15);
  const int e = hbase >> 6;
#pragma unroll
  for (int j = 0; j < 2; ++j) {
    const int ch = hbase + j * 16;
    const float bx = bias[ch], bg = bias[ch + 32];
    const int ac = (ch & 63) + e * 32;
#pragma unroll
    for (int i = 0; i < 2; ++i) {
      const int rr = row0 + i * 16;
#pragma unroll
      for (int r = 0; r < 4; ++r) {
        const float xp = acc[i][j][r] + bx;
        const float g  = acc[i][j + 2][r] + bg;
        const float sg = 1.0f / (1.0f + __expf(-g));
        const float pr = probs[(size_t)(rr + r) * 4 + e];
        a2[(size_t)(rr + r) * 128 + ac] = (bf16_t)(pr * xp * g * sg);
      }
    }
  }
}

// ---------------------------------------------------------------------------
// moe-GEMM (K=128) with fused kv_new epilogue (fp32 out).
// ---------------------------------------------------------------------------
__global__ __launch_bounds__(256)
void gemm_moe_kvnew(const bf16_t* __restrict__ A, const bf16_t* __restrict__ Wt,
                    const float* __restrict__ kv, const float* __restrict__ probs,
                    const float* __restrict__ b2, const float* __restrict__ gate_ffn,
                    float* __restrict__ out) {
  __shared__ alignas(16) bf16_t As[2 * 128 * 32];
  __shared__ alignas(16) bf16_t Bs[2 * 128 * 32];
  const int K = 128, N = D_;
  const int tid = threadIdx.x;
  const int lane = tid & 63;
  const int w = tid >> 6;
  const int wr = w >> 1, wc = w & 1;
  const int m0 = xcd_swz(blockIdx.x, gridDim.x) * 128;
  const int n0 = blockIdx.y * 128;

  f32x4 acc[4][4] = {};
  const bf16_t* ga = A  + (size_t)(m0 + (tid >> 2)) * K + (tid & 3) * 8;
  const bf16_t* gb = Wt + (size_t)(n0 + (tid >> 2)) * K + (tid & 3) * 8;
  const int kb = (lane >> 4) * 8;
  const int ar  = ((wr * 64 + (lane & 15)) << 5) + kb;
  const int br2 = ((wc * 64 + (lane & 15)) << 5) + kb;

  gemm_loop_db(ga, gb, As, Bs, K, (size_t)64 * K, ar, br2, tid, acc);

  const float sgf = 1.0f / (1.0f + __expf(-gate_ffn[0]));
  const int row0 = m0 + wr * 64 + ((lane >> 4) << 2);
  const int col0 = n0 + wc * 64 + (lane & 15);
#pragma unroll
  for (int j = 0; j < 4; ++j) {
    const int cc = col0 + j * 16;
    const f32x4 b2v = { b2[0 * D_ + cc], b2[1 * D_ + cc], b2[2 * D_ + cc], b2[3 * D_ + cc] };
#pragma unroll
    for (int i = 0; i < 4; ++i) {
      const int rr = row0 + i * 16;
#pragma unroll
      for (int r = 0; r < 4; ++r) {
        const f32x4 pr = *(const f32x4*)&probs[(size_t)(rr + r) * 4];
        const float bsum = pr[0]*b2v[0] + pr[1]*b2v[1] + pr[2]*b2v[2] + pr[3]*b2v[3];
        out[(size_t)(rr + r) * N + cc] =
            kv[(size_t)(rr + r) * N + cc] + sgf * (acc[i][j][r] + bsum);
      }
    }
  }
}

// ---------------------------------------------------------------------------
// MFMA flash attention, two segments, no-max exp2 softmax, swapped QK^T.
// Block = 128 thr (2 waves) = (b, h, 64 q-rows); each wave 32 rows via two
// Q-frag sets. Grid 1024 -> 4 independent blocks/CU (LDS 40KB).
// ---------------------------------------------------------------------------
__global__ __launch_bounds__(128, 2)
void attn_mfma_kernel(const bf16_t* __restrict__ qp, const bf16_t* __restrict__ kb,
                      const bf16_t* __restrict__ vt, bf16_t* __restrict__ attno,
                      const float* __restrict__ log_temp, const int* __restrict__ n_act) {
  __shared__ alignas(16) bf16_t Ks[2][64 * 64];
  __shared__ alignas(16) bf16_t Vs[2][64 * 64];
  __shared__ alignas(16) bf16_t Ps[2][32 * 64];

  const int dd = blockIdx.x;
  const int xcd = dd & 7, within = dd >> 3;       // 8 q-tiles per (b,h) share XCD
  const int qt = within & 7, slot0 = within >> 3;
  const int bh = slot0 * 8 + xcd;
  const int b = bh >> 4, h = bh & 15;

  const int tid = threadIdx.x;
  const int lane = tid & 63;
  const int w = tid >> 6;                          // 0..1
  const int lane15 = lane & 15, lgrp = lane >> 4, l7 = lane & 7;
  const int Na = n_act[0];
  float temp = __expf(log_temp[0]);
  temp = fminf(fmaxf(temp, 0.1f), 10.0f);
  const float lsc = LOG2E / (64.0f * temp);
  const int rowbase = qt * 64 + w * 32;

  // Two Q B-frag sets, pre-scaled
  const bf16_t* qsrcA = qp + (size_t)(b * TQ_ + rowbase + lane15) * D_ + h * 64 + lgrp * 8;
  const bf16_t* qsrcB = qsrcA + (size_t)16 * D_;
  bf16x8 qfA0 = *(const bf16x8*)qsrcA;
  bf16x8 qfA1 = *(const bf16x8*)(qsrcA + 32);
  bf16x8 qfB0 = *(const bf16x8*)qsrcB;
  bf16x8 qfB1 = *(const bf16x8*)(qsrcB + 32);
#pragma unroll
  for (int j = 0; j < 8; ++j) {
    qfA0[j] = (bf16_t)((float)qfA0[j] * lsc);
    qfA1[j] = (bf16_t)((float)qfA1[j] * lsc);
    qfB0[j] = (bf16_t)((float)qfB0[j] * lsc);
    qfB1[j] = (bf16_t)((float)qfB1[j] * lsc);
  }

  // staging: 128 thr x 16B = 2KB = 16 rows/issue; 4 issues per 64x64 tile.
  const int srow = tid >> 3;                       // 0..15
  const int schunk = (tid & 7) ^ (srow & 7);       // (srow+16k)&7 == srow&7
  const bf16_t* ksrc = kb + (size_t)(b * TK_ + srow) * D_ + h * 64 + schunk * 8;
  const bf16_t* vsrc = vt + ((size_t)(b * 16 + h) * 64 + srow) * TK_ + schunk * 8;

  f32x4 oA[4] = {}, oB[4] = {}, outA[4] = {}, outB[4] = {};
  float laccA = 0.f, laccB = 0.f;

  const float inv_sa = rsqrtf((float)(Na > 1 ? Na : 1));
  const int Ni = TK_ - Na;
  const float inv_si = rsqrtf((float)(Ni > 1 ? Ni : 1));

#pragma unroll
  for (int r = 0; r < 4; ++r) {
    gld_lds16(ksrc + (size_t)r * 16 * D_, &Ks[0][r * 1024 + tid * 8]);
    gld_lds16(vsrc + (size_t)r * 16 * TK_, &Vs[0][r * 1024 + tid * 8]);
  }

  for (int t = 0; t < TK_ / 64; ++t) {
    const int cur = t & 1;
    __syncthreads();
    if (t + 1 < TK_ / 64) {
      const int nb = cur ^ 1;
      const bf16_t* kN = ksrc + (size_t)(t + 1) * 64 * D_;
      const bf16_t* vN = vsrc + (size_t)(t + 1) * 64;
#pragma unroll
      for (int r = 0; r < 4; ++r) {
        gld_lds16(kN + (size_t)r * 16 * D_, &Ks[nb][r * 1024 + tid * 8]);
        gld_lds16(vN + (size_t)r * 16 * TK_, &Vs[nb][r * 1024 + tid * 8]);
      }
    }

    // ---- S^T = K @ Q for both sets (K frags shared) ----
    f32x4 sA[4], sB[4];
    __builtin_amdgcn_s_setprio(1);
#pragma unroll
    for (int cf = 0; cf < 4; ++cf) {
      const int krow = (cf * 16 + lane15) * 64;
      const bf16x8 kf0 = *(const bf16x8*)&Ks[cur][krow + ((lgrp ^ l7) << 3)];
      const bf16x8 kf1 = *(const bf16x8*)&Ks[cur][krow + (((lgrp + 4) ^ l7) << 3)];
      f32x4 s = {};
      s = __builtin_amdgcn_mfma_f32_16x16x32_bf16(kf0, qfA0, s, 0, 0, 0);
      s = __builtin_amdgcn_mfma_f32_16x16x32_bf16(kf1, qfA1, s, 0, 0, 0);
      sA[cf] = s;
      f32x4 s2 = {};
      s2 = __builtin_amdgcn_mfma_f32_16x16x32_bf16(kf0, qfB0, s2, 0, 0, 0);
      s2 = __builtin_amdgcn_mfma_f32_16x16x32_bf16(kf1, qfB1, s2, 0, 0, 0);
      sB[cf] = s2;
    }
    __builtin_amdgcn_s_setprio(0);

    // ---- p = exp2(s); lane-local l; packed bf16x4 P stores ----
#pragma unroll
    for (int cf = 0; cf < 4; ++cf) {
      const int c = cf * 2 + (lgrp >> 1);
      const int pcol = ((c ^ l7) << 3) + (lgrp & 1) * 4;
      f32x4 pA, pB;
#pragma unroll
      for (int r = 0; r < 4; ++r) pA[r] = exp2f(sA[cf][r]);
#pragma unroll
      for (int r = 0; r < 4; ++r) pB[r] = exp2f(sB[cf][r]);
      laccA += (pA[0] + pA[1]) + (pA[2] + pA[3]);
      laccB += (pB[0] + pB[1]) + (pB[2] + pB[3]);
      bf16x4 pvA, pvB;
#pragma unroll
      for (int r = 0; r < 4; ++r) { pvA[r] = (bf16_t)pA[r]; pvB[r] = (bf16_t)pB[r]; }
      *(bf16x4*)&Ps[w][lane15 * 64 + pcol]        = pvA;
      *(bf16x4*)&Ps[w][(16 + lane15) * 64 + pcol] = pvB;
    }

    // ---- O += P @ V for both sets (V frags shared) ----
    {
      const int prowA = lane15 * 64;
      const int prowB = (16 + lane15) * 64;
      const bf16x8 paA0 = *(const bf16x8*)&Ps[w][prowA + ((lgrp ^ l7) << 3)];
      const bf16x8 paA1 = *(const bf16x8*)&Ps[w][prowA + (((lgrp + 4) ^ l7) << 3)];
      const bf16x8 paB0 = *(const bf16x8*)&Ps[w][prowB + ((lgrp ^ l7) << 3)];
      const bf16x8 paB1 = *(const bf16x8*)&Ps[w][prowB + (((lgrp + 4) ^ l7) << 3)];
      __builtin_amdgcn_s_setprio(1);
#pragma unroll
      for (int df = 0; df < 4; ++df) {
        const int vrow = (df * 16 + lane15) * 64;
        const bf16x8 vf0 = *(const bf16x8*)&Vs[cur][vrow + ((lgrp ^ l7) << 3)];
        const bf16x8 vf1 = *(const bf16x8*)&Vs[cur][vrow + (((lgrp + 4) ^ l7) << 3)];
        oA[df] = __builtin_amdgcn_mfma_f32_16x16x32_bf16(paA0, vf0, oA[df], 0, 0, 0);
        oA[df] = __builtin_amdgcn_mfma_f32_16x16x32_bf16(paA1, vf1, oA[df], 0, 0, 0);
        oB[df] = __builtin_amdgcn_mfma_f32_16x16x32_bf16(paB0, vf0, oB[df], 0, 0, 0);
        oB[df] = __builtin_amdgcn_mfma_f32_16x16x32_bf16(paB1, vf1, oB[df], 0, 0, 0);
      }
      __builtin_amdgcn_s_setprio(0);
    }

    // ---- segment finalize ----
    const bool endA = ((t + 1) * 64 == Na);
    const bool endI = (t == TK_ / 64 - 1);
    if (endA || endI) {
      float lA = laccA, lB = laccB;
      lA += __shfl_xor(lA, 16); lA += __shfl_xor(lA, 32);
      lB += __shfl_xor(lB, 16); lB += __shfl_xor(lB, 32);
      const float ssc = endA ? inv_sa : -inv_si;
      f32x4 ivA, ivB;
#pragma unroll
      for (int r = 0; r < 4; ++r) {
        ivA[r] = ssc / __shfl(lA, lgrp * 4 + r);
        ivB[r] = ssc / __shfl(lB, lgrp * 4 + r);
      }
#pragma unroll
      for (int df = 0; df < 4; ++df) {
        outA[df] += oA[df] * ivA; oA[df] = (f32x4){};
        outB[df] += oB[df] * ivB; oB[df] = (f32x4){};
      }
      laccA = 0.f; laccB = 0.f;
    }
  }

#pragma unroll
  for (int df = 0; df < 4; ++df)
#pragma unroll
    for (int r = 0; r < 4; ++r) {
      const size_t ro = (size_t)(b * TQ_ + rowbase + lgrp * 4 + r) * D_ + h * 64 + df * 16 + lane15;
      attno[ro]           = (bf16_t)outA[df][r];
      attno[ro + 16 * D_] = (bf16_t)outB[df][r];
    }
}

// ---------------------------------------------------------------------------
// delta = rmsnorm(proj, dn_w); q_new = q + sigmoid(gate_attn)*delta (fp32 out)
// ---------------------------------------------------------------------------
__global__ __launch_bounds__(256)
void delta_qnew_kernel(const bf16_t* __restrict__ proj, const float* __restrict__ dn_w,
                       const float* __restrict__ q, const float* __restrict__ gate_attn,
                       float* __restrict__ qnew) {
  __shared__ float red[4];
  const int row = blockIdx.x;
  const int tid = threadIdx.x;
  bf16x4 pv = *(const bf16x4*)(proj + (size_t)row * D_ + tid * 4);
  f32x4 v;
#pragma unroll
  for (int c = 0; c < 4; ++c) v[c] = (float)pv[c];
  float ss = v[0]*v[0] + v[1]*v[1] + v[2]*v[2] + v[3]*v[3];
  ss = block_rsum(ss, red);
  const float rs = rsqrtf(ss * (1.0f / D_) + EPSF);
  const float sga = 1.0f / (1.0f + __expf(-gate_attn[0]));
  const int d = tid * 4;
  f32x4 wv = *(const f32x4*)(dn_w + d);
  f32x4 qv = *(const f32x4*)(q + (size_t)row * D_ + d);
  f32x4 out;
#pragma unroll
  for (int c = 0; c < 4; ++c) out[c] = qv[c] + sga * (v[c] * rs * wv[c]);
  *(f32x4*)&qnew[(size_t)row * D_ + d] = out;
}

// ---------------------------------------------------------------------------
extern "C" void kernel_launch(void* const* d_in, const int* in_sizes, int n_in,
                              void* d_out, int out_size, void* d_ws, size_t ws_size,
                              hipStream_t stream) {
  const float* q           = (const float*)d_in[0];
  const float* kv          = (const float*)d_in[1];
  const float* qn_w        = (const float*)d_in[2];
  const float* kva_w       = (const float*)d_in[3];
  const float* kvi_w       = (const float*)d_in[4];
  const float* dn_w        = (const float*)d_in[5];
  const float* fn_w        = (const float*)d_in[6];
  const float* Wq          = (const float*)d_in[7];
  const float* bq          = (const float*)d_in[8];
  const float* Wk          = (const float*)d_in[9];
  const float* bk          = (const float*)d_in[10];
  const float* Wv          = (const float*)d_in[11];
  const float* bv          = (const float*)d_in[12];
  const float* Wo          = (const float*)d_in[13];
  const float* bo          = (const float*)d_in[14];
  const float* active_bias = (const float*)d_in[15];
  const float* inactive_b  = (const float*)d_in[16];
  const float* log_temp    = (const float*)d_in[17];
  const float* gate_attn   = (const float*)d_in[18];
  const float* gate_ffn    = (const float*)d_in[19];
  const float* Wr          = (const float*)d_in[20];
  const float* br          = (const float*)d_in[21];
  const float* W1          = (const float*)d_in[22];
  const float* b1          = (const float*)d_in[23];
  const float* W2          = (const float*)d_in[24];
  const float* b2          = (const float*)d_in[25];
  const int*   n_act       = (const int*)d_in[27];

  char* ws = (char*)d_ws;
  size_t off = 0;
  auto alloc = [&](size_t bytes) -> char* {
    char* p = ws + off;
    off = (off + bytes + 255) & ~(size_t)255;
    return p;
  };

  bf16_t* wqT  = (bf16_t*)alloc((size_t)D_ * D_ * 2);
  bf16_t* wkT  = (bf16_t*)alloc((size_t)D_ * D_ * 2);   // frag-ordered
  bf16_t* wvT  = (bf16_t*)alloc((size_t)D_ * D_ * 2);   // frag-ordered
  bf16_t* woT  = (bf16_t*)alloc((size_t)D_ * D_ * 2);
  bf16_t* w1T  = (bf16_t*)alloc((size_t)256 * D_ * 2);
  bf16_t* w2T  = (bf16_t*)alloc((size_t)D_ * 128 * 2);
  bf16_t* kvb  = (bf16_t*)alloc((size_t)B_ * TK_ * D_ * 2);  // frag-ordered
  bf16_t* xn   = (bf16_t*)alloc((size_t)B_ * TK_ * D_ * 2);
  bf16_t* qn   = (bf16_t*)alloc((size_t)B_ * TQ_ * D_ * 2);
  bf16_t* qp   = (bf16_t*)alloc((size_t)B_ * TQ_ * D_ * 2);
  bf16_t* kbuf = (bf16_t*)alloc((size_t)B_ * TK_ * D_ * 2);
  bf16_t* vt   = (bf16_t*)alloc((size_t)B_ * D_ * TK_ * 2);
  float*  probs = (float*)alloc((size_t)B_ * TK_ * NE_ * 4);
  bf16_t* attno = qn;    // qn consumed by qp GEMM before attention writes
  bf16_t* proj  = qp;    // qp consumed by attention before proj GEMM writes
  bf16_t* a2buf = kbuf;  // kbuf consumed by attention before h-act writes
  (void)ws_size; (void)in_sizes; (void)n_in; (void)out_size;

  float* q_new_out  = (float*)d_out;
  float* kv_new_out = (float*)d_out + (size_t)B_ * TQ_ * D_;

  dim3 tb(32, 8);
  TP2 tpa; tpa.in[0] = Wq; tpa.in[1] = Wo; tpa.out[0] = wqT; tpa.out[1] = woT;
  transpose_conv2_kernel<<<dim3(32, 32, 2), tb, 0, stream>>>(tpa);
  TP2 tpf; tpf.in[0] = Wk; tpf.in[1] = Wv; tpf.out[0] = wkT; tpf.out[1] = wvT;
  transpose_fragorder_kernel<<<dim3(32, 32, 2), tb, 0, stream>>>(tpf);
  transpose_conv_kernel<<<dim3(2, 32, 4), tb, 0, stream>>>(W1, w1T, D_, 64, D_ * 64, D_, 64, 0);
  transpose_conv_kernel<<<dim3(32, 1, 4), tb, 0, stream>>>(W2, w2T, 32, D_, 32 * D_, 128, 0, 32);

  rms_kv_kernel<<<B_ * TK_, 256, 0, stream>>>(kv, kva_w, kvi_w, fn_w, active_bias,
                                              inactive_b, n_act, Wr, br, kvb, xn, probs);
  rms_q_kernel<<<B_ * TQ_, 256, 0, stream>>>(q, qn_w, qn);

  gemm64_tn<1><<<dim3(B_ * TQ_ / 64, D_ / 128), 256, 0, stream>>>(qn, wqT, bq, qp, B_ * TQ_, D_, D_);
  // fused K + V(transposed) projections, frag-ordered inputs
  gemm_kv<<<B_ * TK_ / 128 * (D_ / 128), 256, 0, stream>>>(kvb, wkT, wvT, bk, bv, kbuf, vt);

  attn_mfma_kernel<<<B_ * H_ * (TQ_ / 64), 128, 0, stream>>>(qp, kbuf, vt, attno, log_temp, n_act);

  gemm64_tn<1><<<dim3(B_ * TQ_ / 64, D_ / 128), 256, 0, stream>>>(attno, woT, bo, proj, B_ * TQ_, D_, D_);
  delta_qnew_kernel<<<B_ * TQ_, 256, 0, stream>>>(proj, dn_w, q, gate_attn, q_new_out);

  gemm64_h_act<<<dim3(B_ * TK_ / 64, 2), 256, 0, stream>>>(xn, w1T, b1, probs, a2buf);
  gemm_moe_kvnew<<<dim3(B_ * TK_ / 128, D_ / 128), 256, 0, stream>>>(a2buf, w2T, kv, probs, b2,
                                                                     gate_ffn, kv_new_out);
}

// Round 10
// 330.370 us; speedup vs baseline: 1.1098x; 1.0653x over previous
//
#include <hip/hip_runtime.h>
#include <hip/hip_bf16.h>
#include <stdint.h>

// ---------------------------------------------------------------------------
// TransformerBlock fused forward for MI355X (gfx950).
// Shapes (fixed): B=8 TQ=512 TK=2048 D=1024 H=16 HD=64 NE=4 HID=32 NA=512.
//
// Round 10 (gemm_kv only; rest frozen at r9):
//  * depth-2 counted-vmcnt pipeline over 3 LDS buffers (72KB): raw s_barrier
//    + s_waitcnt vmcnt(6) keeps next tile's 6 loads in flight ACROSS the
//    barrier -> each staged load gets ~2 steps (~900+cyc) to land, covering
//    the ~10% HBM-miss tail that gated every step under __syncthreads'
//    mandatory vmcnt(0) drain (r9 measured 2212cyc/step vs 154cyc MFMA).
//    Conflict-free frag-ordered layout retained (r9: conflicts 6.68M->393K).
// ---------------------------------------------------------------------------

#define B_   8
#define TQ_  512
#define TK_  2048
#define D_   1024
#define H_   16
#define HD_  64
#define NE_  4
#define HID_ 32
#define EPSF 1e-6f
#define LOG2E 1.44269504f

typedef __bf16 bf16_t;
typedef __bf16 bf16x8 __attribute__((ext_vector_type(8)));
typedef __bf16 bf16x4 __attribute__((ext_vector_type(4)));
typedef float  f32x4  __attribute__((ext_vector_type(4)));

typedef __attribute__((address_space(1))) void gvoid_t;
typedef __attribute__((address_space(3))) void lvoid_t;

__device__ __forceinline__ void gld_lds16(const void* g, void* l) {
  __builtin_amdgcn_global_load_lds((gvoid_t*)g, (lvoid_t*)l, 16, 0, 0);
}

// ---------------------------------------------------------------------------
// Batched 1024x1024 fp32 -> bf16 transpose (Wq, Wo) to (N,K) row-major.
// ---------------------------------------------------------------------------
struct TP2 { const float* in[2]; bf16_t* out[2]; };

__global__ void transpose_conv2_kernel(TP2 p) {
  __shared__ float tile[32][33];
  const int bz = blockIdx.z;
  const float* in = p.in[bz];
  bf16_t* out = p.out[bz];
  const int rb = blockIdx.y * 32, cb = blockIdx.x * 32;
  const int txi = threadIdx.x, tyi = threadIdx.y;
#pragma unroll
  for (int i = 0; i < 32; i += 8)
    tile[tyi + i][txi] = in[(size_t)(rb + tyi + i) * D_ + cb + txi];
  __syncthreads();
#pragma unroll
  for (int i = 0; i < 32; i += 8)
    out[(size_t)(cb + tyi + i) * D_ + rb + txi] = (bf16_t)tile[txi][tyi + i];
}

// ---------------------------------------------------------------------------
// Frag-ordered weight transpose for Wk/Wv: W(k,n) ->
//   out[tile_n*131072 + s*4096 + hc*2048 + j*512 + (lg*16+l15)*8 + e]
// ---------------------------------------------------------------------------
__global__ void transpose_fragorder_kernel(TP2 p) {
  __shared__ float tile[32][33];
  const float* in = p.in[blockIdx.z];
  bf16_t* out = p.out[blockIdx.z];
  const int kb0 = blockIdx.y * 32;
  const int nb0 = blockIdx.x * 32;
  const int tx = threadIdx.x, ty = threadIdx.y;
#pragma unroll
  for (int i = 0; i < 32; i += 8)
    tile[ty + i][tx] = in[(size_t)(kb0 + ty + i) * D_ + nb0 + tx];
  __syncthreads();
  const int t = ty * 32 + tx;          // 0..255
  const int n_l = t >> 3;              // 0..31
  const int k_l = (t & 7) * 4;         // 0,4,...,28
  const int n = nb0 + n_l;
  const int k = kb0 + k_l;
  const int tile_n = n >> 7, rn = n & 127, hc = rn >> 6, rr = rn & 63;
  const int j = rr >> 4, l15 = rr & 15;
  const int s = k >> 5, lg = (k >> 3) & 3, e = k & 7;
  bf16x4 o;
#pragma unroll
  for (int c = 0; c < 4; ++c) o[c] = (bf16_t)tile[k_l + c][n_l];
  *(bf16x4*)&out[(size_t)tile_n * 131072 + s * 4096 + hc * 2048 +
                 j * 512 + (lg * 16 + l15) * 8 + e] = o;
}

// Generic small transpose (W1/W2).
__global__ void transpose_conv_kernel(const float* __restrict__ in, bf16_t* __restrict__ out,
                                      int R, int C, int in_bstride,
                                      int out_rstride, int ob_row, int ob_col) {
  __shared__ float tile[32][33];
  const int bz = blockIdx.z;
  const int rb = blockIdx.y * 32, cb = blockIdx.x * 32;
  const int txi = threadIdx.x, tyi = threadIdx.y;
  const float* inp = in + (size_t)bz * in_bstride;
#pragma unroll
  for (int i = 0; i < 32; i += 8) {
    const int r = rb + tyi + i, c = cb + txi;
    if (r < R && c < C) tile[tyi + i][txi] = inp[(size_t)r * C + c];
  }
  __syncthreads();
#pragma unroll
  for (int i = 0; i < 32; i += 8) {
    const int orow = cb + tyi + i;
    const int ocol = rb + txi;
    if (orow < C && ocol < R)
      out[(size_t)(orow + bz * ob_row) * out_rstride + bz * ob_col + ocol] =
          (bf16_t)tile[txi][tyi + i];
  }
}

__device__ __forceinline__ float block_rsum(float v, float* red) {
  v += __shfl_xor(v, 1);  v += __shfl_xor(v, 2);  v += __shfl_xor(v, 4);
  v += __shfl_xor(v, 8);  v += __shfl_xor(v, 16); v += __shfl_xor(v, 32);
  const int tid = threadIdx.x;
  if ((tid & 63) == 0) red[tid >> 6] = v;
  __syncthreads();
  return red[0] + red[1] + red[2] + red[3];
}

// ---------------------------------------------------------------------------
// RMSNorm of kv -> kvb (seg weights+bias, FRAG-ORDERED for gemm_kv),
// xn = rmsnorm(kv,fn_w) (row-major), probs = softmax(x@Wr + br).
// ---------------------------------------------------------------------------
__global__ __launch_bounds__(256)
void rms_kv_kernel(const float* __restrict__ kv, const float* __restrict__ kva_w,
                   const float* __restrict__ kvi_w, const float* __restrict__ fn_w,
                   const float* __restrict__ ab, const float* __restrict__ ib,
                   const int* __restrict__ n_act, const float* __restrict__ Wr,
                   const float* __restrict__ br,
                   bf16_t* __restrict__ kvb, bf16_t* __restrict__ xn,
                   float* __restrict__ probs) {
  __shared__ float red[4];
  __shared__ f32x4 pred[4];
  const int row = blockIdx.x;
  const int t = row & (TK_ - 1);
  const int tid = threadIdx.x;
  const float* src = kv + (size_t)row * D_;
  f32x4 v = ((const f32x4*)src)[tid];
  float ss = v[0]*v[0] + v[1]*v[1] + v[2]*v[2] + v[3]*v[3];
  ss = block_rsum(ss, red);
  const float rs = rsqrtf(ss * (1.0f / D_) + EPSF);
  const int Na = n_act[0];
  const float* wsel = (t < Na) ? kva_w : kvi_w;
  const float* bsel = (t < Na) ? ab : ib;
  const int d = tid * 4;
  f32x4 wv = *(const f32x4*)(wsel + d);
  f32x4 bv = *(const f32x4*)(bsel + d);
  f32x4 fv = *(const f32x4*)(fn_w + d);
  bf16x4 o0, o1;
  f32x4 p4 = {};
#pragma unroll
  for (int c = 0; c < 4; ++c) {
    const float xv = v[c] * rs;
    const float xf = xv * fv[c];
    o0[c] = (bf16_t)(xv * wv[c] + bv[c]);
    o1[c] = (bf16_t)xf;
    const f32x4 w4 = *(const f32x4*)&Wr[(d + c) * 4];
    p4 += w4 * xf;
  }
  // kvb frag-ordered: row -> (tile_m, h, i, l15); d -> (s, lg, e)
  {
    const int rl = row & 127, hh = rl >> 6, rr2 = rl & 63;
    const int ii = rr2 >> 4, l15 = rr2 & 15;
    const int s2 = d >> 5, lg2 = (d >> 3) & 3, e2 = d & 7;
    *(bf16x4*)&kvb[(size_t)(row >> 7) * 131072 + s2 * 4096 + hh * 2048 +
                   ii * 512 + (lg2 * 16 + l15) * 8 + e2] = o0;
  }
  *(bf16x4*)&xn[(size_t)row * D_ + d] = o1;
#pragma unroll
  for (int m = 1; m <= 32; m <<= 1) {
    p4[0] += __shfl_xor(p4[0], m); p4[1] += __shfl_xor(p4[1], m);
    p4[2] += __shfl_xor(p4[2], m); p4[3] += __shfl_xor(p4[3], m);
  }
  if ((tid & 63) == 0) pred[tid >> 6] = p4;
  __syncthreads();
  if (tid == 0) {
    f32x4 s = pred[0] + pred[1] + pred[2] + pred[3];
    s[0] += br[0]; s[1] += br[1]; s[2] += br[2]; s[3] += br[3];
    const float mx = fmaxf(fmaxf(s[0], s[1]), fmaxf(s[2], s[3]));
    const float e0 = __expf(s[0] - mx), e1 = __expf(s[1] - mx);
    const float e2 = __expf(s[2] - mx), e3 = __expf(s[3] - mx);
    const float inv = 1.0f / (e0 + e1 + e2 + e3);
    f32x4 pr = { e0 * inv, e1 * inv, e2 * inv, e3 * inv };
    *(f32x4*)&probs[row * 4] = pr;
  }
}

__global__ __launch_bounds__(256)
void rms_q_kernel(const float* __restrict__ q, const float* __restrict__ qn_w,
                  bf16_t* __restrict__ qn) {
  __shared__ float red[4];
  const int row = blockIdx.x;
  const int tid = threadIdx.x;
  const float* src = q + (size_t)row * D_;
  f32x4 v = ((const f32x4*)src)[tid];
  float ss = v[0]*v[0] + v[1]*v[1] + v[2]*v[2] + v[3]*v[3];
  ss = block_rsum(ss, red);
  const float rs = rsqrtf(ss * (1.0f / D_) + EPSF);
  const int d = tid * 4;
  f32x4 wv = *(const f32x4*)(qn_w + d);
  bf16x4 o0;
#pragma unroll
  for (int c = 0; c < 4; ++c) o0[c] = (bf16_t)(v[c] * rs * wv[c]);
  *(bf16x4*)&qn[(size_t)row * D_ + d] = o0;
}

__device__ __forceinline__ int xcd_swz(int bx, int gx) {
  if ((gx & 7) == 0) { const int cpx = gx >> 3; return (bx & 7) * cpx + (bx >> 3); }
  return bx;
}

// ---------------------------------------------------------------------------
// FUSED K+V projection GEMM, frag-ordered inputs, depth-2 counted-vmcnt
// pipeline over 3 LDS buffers.
//   A: kvb frag-ordered [tile_m][s][h][i][lane][8]
//   B: wk/wv frag-ordered [tile_n][s][hc][j][lane][8]
// Per step s: waitcnt vmcnt(6) [tile s's 6 loads done; tile s+1's 6 stay in
// flight ACROSS the barrier] -> s_barrier -> frag reads -> STAGE(s+2) ->
// 32 MFMA. vmcnt(0) only for the last two steps.
// ---------------------------------------------------------------------------
__global__ __launch_bounds__(256)
void gemm_kv(const bf16_t* __restrict__ A, const bf16_t* __restrict__ Wk,
             const bf16_t* __restrict__ Wv, const float* __restrict__ bk,
             const float* __restrict__ bv, bf16_t* __restrict__ Kout,
             bf16_t* __restrict__ Vt) {
  __shared__ alignas(16) bf16_t lds[3 * 12288];  // 3 bufs x (A 8KB|Bk 8KB|Bv 8KB)
  const int tid = threadIdx.x;
  const int lane = tid & 63;
  const int w = tid >> 6;
  const int wr = w >> 1, wc = w & 1;
  const int lane15 = lane & 15, lgrp = lane >> 4;

  // batch-per-XCD decomposition (1024 blocks)
  const int flat = blockIdx.x;
  const int xcd = flat & 7;
  const int local = flat >> 3;
  const int tg = local >> 3;
  const int yy = local & 7;
  const int m0 = (xcd * 16 + tg) * 128;
  const int n0 = yy * 128;

  f32x4 acc_k[4][4] = {};
  f32x4 acc_v[4][4] = {};

  const bf16_t* ga = A  + (size_t)(m0 >> 7) * 131072 + tid * 8;
  const bf16_t* gk = Wk + (size_t)(n0 >> 7) * 131072 + tid * 8;
  const bf16_t* gv = Wv + (size_t)(n0 >> 7) * 131072 + tid * 8;

  auto STAGE = [&](int s) {
    bf16_t* dst = lds + (s % 3) * 12288 + tid * 8;
    const size_t so = (size_t)s * 4096;
    gld_lds16(ga + so,        dst);
    gld_lds16(ga + so + 2048, dst + 2048);
    gld_lds16(gk + so,        dst + 4096);
    gld_lds16(gk + so + 2048, dst + 6144);
    gld_lds16(gv + so,        dst + 8192);
    gld_lds16(gv + so + 2048, dst + 10240);
  };

  STAGE(0);
  STAGE(1);

  const int abase = wr * 2048 + lane * 8;
  const int bbase = wc * 2048 + lane * 8;
  for (int s = 0; s < 32; ++s) {
    if (s < 30) asm volatile("s_waitcnt vmcnt(6)" ::: "memory");
    else        asm volatile("s_waitcnt vmcnt(0)" ::: "memory");
    __builtin_amdgcn_s_barrier();
    __builtin_amdgcn_sched_barrier(0);
    const bf16_t* buf = lds + (s % 3) * 12288;
    bf16x8 af[4], bkf[4], bvf[4];
#pragma unroll
    for (int i = 0; i < 4; ++i) af[i]  = *(const bf16x8*)&buf[abase + i * 512];
#pragma unroll
    for (int j = 0; j < 4; ++j) bkf[j] = *(const bf16x8*)&buf[4096 + bbase + j * 512];
#pragma unroll
    for (int j = 0; j < 4; ++j) bvf[j] = *(const bf16x8*)&buf[8192 + bbase + j * 512];
    if (s + 2 < 32) STAGE(s + 2);
    __builtin_amdgcn_s_setprio(1);
#pragma unroll
    for (int i = 0; i < 4; ++i)
#pragma unroll
      for (int j = 0; j < 4; ++j) {
        acc_k[i][j] = __builtin_amdgcn_mfma_f32_16x16x32_bf16(af[i], bkf[j], acc_k[i][j], 0, 0, 0);
        acc_v[i][j] = __builtin_amdgcn_mfma_f32_16x16x32_bf16(af[i], bvf[j], acc_v[i][j], 0, 0, 0);
      }
    __builtin_amdgcn_s_setprio(0);
  }

  // ---- K epilogue: Kout[tok][n] ----
  const int row0 = m0 + wr * 64 + (lgrp << 2);
  const int col0 = n0 + wc * 64 + lane15;
#pragma unroll
  for (int j = 0; j < 4; ++j) {
    const int cc = col0 + j * 16;
    const float bkv = bk[cc];
#pragma unroll
    for (int i = 0; i < 4; ++i) {
      const int rr = row0 + i * 16;
#pragma unroll
      for (int r = 0; r < 4; ++r)
        Kout[(size_t)(rr + r) * D_ + cc] = (bf16_t)(acc_k[i][j][r] + bkv);
    }
  }

  // ---- V epilogue: packed transpose via LDS, write vt[b][n][tok] ----
  __syncthreads();                       // mainloop LDS reads done; reuse lds
  bf16_t* vt_l = lds + w * 4608;         // 64 x 72 per wave (9216 B)
#pragma unroll
  for (int j = 0; j < 4; ++j) {
    const int nl = j * 16 + lane15;
    const float bvv = bv[n0 + wc * 64 + nl];
#pragma unroll
    for (int i = 0; i < 4; ++i) {
      bf16x4 pv;
#pragma unroll
      for (int r = 0; r < 4; ++r) pv[r] = (bf16_t)(acc_v[i][j][r] + bvv);
      *(bf16x4*)&vt_l[nl * 72 + i * 16 + lgrp * 4] = pv;   // 4 consecutive tok
    }
  }
  const int bidx2 = m0 >> 11;                          // batch
  const int tok0 = (m0 & (TK_ - 1)) + wr * 64;
  bf16_t* vbase = Vt + (size_t)bidx2 * D_ * TK_ + (size_t)(n0 + wc * 64) * TK_ + tok0;
#pragma unroll
  for (int it = 0; it < 8; ++it) {
    const int ln = (lane >> 3) + it * 8;
    const int tk = (lane & 7) * 8;
    const bf16x8 v8 = *(const bf16x8*)&vt_l[ln * 72 + tk];
    *(bf16x8*)&vbase[(size_t)ln * TK_ + tk] = v8;
  }
}

// ---------------------------------------------------------------------------
// Shared 128x128 GEMM mainloop (BK=32, dbuf) — used by moe GEMM.
// ---------------------------------------------------------------------------
__device__ __forceinline__ void gemm_loop_db(const bf16_t* __restrict__ ga,
                                             const bf16_t* __restrict__ gb,
                                             bf16_t* As, bf16_t* Bs, int K,
                                             size_t rstep, int ar, int br2,
                                             int tid, f32x4 acc[4][4]) {
  gld_lds16(ga,         &As[tid * 8]);
  gld_lds16(ga + rstep, &As[2048 + tid * 8]);
  gld_lds16(gb,         &Bs[tid * 8]);
  gld_lds16(gb + rstep, &Bs[2048 + tid * 8]);
  int buf = 0;
  for (int k0 = 0; k0 < K; k0 += 32) {
    __syncthreads();
    if (k0 + 32 < K) {
      const int nb = buf ^ 1;
      gld_lds16(ga + k0 + 32,         &As[nb * 4096 + tid * 8]);
      gld_lds16(ga + k0 + 32 + rstep, &As[nb * 4096 + 2048 + tid * 8]);
      gld_lds16(gb + k0 + 32,         &Bs[nb * 4096 + tid * 8]);
      gld_lds16(gb + k0 + 32 + rstep, &Bs[nb * 4096 + 2048 + tid * 8]);
    }
    bf16x8 af[4], bfr[4];
#pragma unroll
    for (int i = 0; i < 4; ++i) af[i]  = *(const bf16x8*)&As[buf * 4096 + ar  + i * 512];
#pragma unroll
    for (int j = 0; j < 4; ++j) bfr[j] = *(const bf16x8*)&Bs[buf * 4096 + br2 + j * 512];
#pragma unroll
    for (int i = 0; i < 4; ++i)
#pragma unroll
      for (int j = 0; j < 4; ++j)
        acc[i][j] = __builtin_amdgcn_mfma_f32_16x16x32_bf16(af[i], bfr[j], acc[i][j], 0, 0, 0);
    buf ^= 1;
  }
}

// ---------------------------------------------------------------------------
// Shared 64x128 GEMM mainloop (BK=32, dbuf) — small-M GEMMs.
// ---------------------------------------------------------------------------
__device__ __forceinline__ void gemm64_loop_db(const bf16_t* __restrict__ ga,
                                               const bf16_t* __restrict__ gb,
                                               bf16_t* As, bf16_t* Bs, int K,
                                               size_t rstep, int ar, int br2,
                                               int tid, f32x4 acc[2][4]) {
  gld_lds16(ga,         &As[tid * 8]);
  gld_lds16(gb,         &Bs[tid * 8]);
  gld_lds16(gb + rstep, &Bs[2048 + tid * 8]);
  int buf = 0;
  for (int k0 = 0; k0 < K; k0 += 32) {
    __syncthreads();
    if (k0 + 32 < K) {
      const int nb = buf ^ 1;
      gld_lds16(ga + k0 + 32,         &As[nb * 2048 + tid * 8]);
      gld_lds16(gb + k0 + 32,         &Bs[nb * 4096 + tid * 8]);
      gld_lds16(gb + k0 + 32 + rstep, &Bs[nb * 4096 + 2048 + tid * 8]);
    }
    bf16x8 af[2], bfr[4];
#pragma unroll
    for (int i = 0; i < 2; ++i) af[i]  = *(const bf16x8*)&As[buf * 2048 + ar  + i * 512];
#pragma unroll
    for (int j = 0; j < 4; ++j) bfr[j] = *(const bf16x8*)&Bs[buf * 4096 + br2 + j * 512];
#pragma unroll
    for (int i = 0; i < 2; ++i)
#pragma unroll
      for (int j = 0; j < 4; ++j)
        acc[i][j] = __builtin_amdgcn_mfma_f32_16x16x32_bf16(af[i], bfr[j], acc[i][j], 0, 0, 0);
    buf ^= 1;
  }
}

// ---------------------------------------------------------------------------
// 64x128 GEMM: C = A @ Wt^T (+bias[N]) — qp / proj.
// ---------------------------------------------------------------------------
template<int HAS_BIAS>
__global__ __launch_bounds__(256)
void gemm64_tn(const bf16_t* __restrict__ A, const bf16_t* __restrict__ Wt,
               const float* __restrict__ bias, bf16_t* __restrict__ C,
               int M, int N, int K) {
  __shared__ alignas(16) bf16_t As[2 * 64 * 32];
  __shared__ alignas(16) bf16_t Bs[2 * 128 * 32];
  const int tid = threadIdx.x;
  const int lane = tid & 63;
  const int w = tid >> 6;
  const int wr = w >> 1, wc = w & 1;
  const int m0 = xcd_swz(blockIdx.x, gridDim.x) * 64;
  const int n0 = blockIdx.y * 128;

  f32x4 acc[2][4] = {};
  const bf16_t* ga = A  + (size_t)(m0 + (tid >> 2)) * K + (tid & 3) * 8;
  const bf16_t* gb = Wt + (size_t)(n0 + (tid >> 2)) * K + (tid & 3) * 8;
  const int kb = (lane >> 4) * 8;
  const int ar  = ((wr * 32 + (lane & 15)) << 5) + kb;
  const int br2 = ((wc * 64 + (lane & 15)) << 5) + kb;

  gemm64_loop_db(ga, gb, As, Bs, K, (size_t)64 * K, ar, br2, tid, acc);

  const int row0 = m0 + wr * 32 + ((lane >> 4) << 2);
  const int col0 = n0 + wc * 64 + (lane & 15);
#pragma unroll
  for (int j = 0; j < 4; ++j) {
    const int cc = col0 + j * 16;
    const float bv = HAS_BIAS ? bias[cc] : 0.0f;
#pragma unroll
    for (int i = 0; i < 2; ++i) {
      const int rr = row0 + i * 16;
#pragma unroll
      for (int r = 0; r < 4; ++r)
        C[(size_t)(rr + r) * N + cc] = (bf16_t)(acc[i][j][r] + bv);
    }
  }
}

// ---------------------------------------------------------------------------
// 64x128-tile h-GEMM with fused bias + SiLU-gate + probs weighting -> a2.
// ---------------------------------------------------------------------------
__global__ __launch_bounds__(256)
void gemm64_h_act(const bf16_t* __restrict__ A, const bf16_t* __restrict__ Wt,
                  const float* __restrict__ bias, const float* __restrict__ probs,
                  bf16_t* __restrict__ a2) {
  __shared__ alignas(16) bf16_t As[2 * 64 * 32];
  __shared__ alignas(16) bf16_t Bs[2 * 128 * 32];
  const int K = D_;
  const int tid = threadIdx.x;
  const int lane = tid & 63;
  const int w = tid >> 6;
  const int wr = w >> 1, wc = w & 1;
  const int m0 = xcd_swz(blockIdx.x, gridDim.x) * 64;
  const int n0 = blockIdx.y * 128;

  f32x4 acc[2][4] = {};
  const bf16_t* ga = A  + (size_t)(m0 + (tid >> 2)) * K + (tid & 3) * 8;
  const bf16_t* gb = Wt + (size_t)(n0 + (tid >> 2)) * K + (tid & 3) * 8;
  const int kb = (lane >> 4) * 8;
  const int ar  = ((wr * 32 + (lane & 15)) << 5) + kb;
  const int br2 = ((wc * 64 + (lane & 15)) << 5) + kb;

  gemm64_loop_db(ga, gb, As, Bs, K, (size_t)64 * K, ar, br2, tid, acc);

  const int row0 = m0 + wr * 32 + ((lane >> 4) << 2);
  const int hbase = n0 + wc * 64 + (lane & 15);
  const int e = hbase >> 6;
#pragma unroll
  for (int j = 0; j < 2; ++j) {
    const int ch = hbase + j * 16;
    const float bx = bias[ch], bg = bias[ch + 32];
    const int ac = (ch & 63) + e * 32;
#pragma unroll
    for (int i = 0; i < 2; ++i) {
      const int rr = row0 + i * 16;
#pragma unroll
      for (int r = 0; r < 4; ++r) {
        const float xp = acc[i][j][r] + bx;
        const float g  = acc[i][j + 2][r] + bg;
        const float sg = 1.0f / (1.0f + __expf(-g));
        const float pr = probs[(size_t)(rr + r) * 4 + e];
        a2[(size_t)(rr + r) * 128 + ac] = (bf16_t)(pr * xp * g * sg);
      }
    }
  }
}

// ---------------------------------------------------------------------------
// moe-GEMM (K=128) with fused kv_new epilogue (fp32 out).
// ---------------------------------------------------------------------------
__global__ __launch_bounds__(256)
void gemm_moe_kvnew(const bf16_t* __restrict__ A, const bf16_t* __restrict__ Wt,
                    const float* __restrict__ kv, const float* __restrict__ probs,
                    const float* __restrict__ b2, const float* __restrict__ gate_ffn,
                    float* __restrict__ out) {
  __shared__ alignas(16) bf16_t As[2 * 128 * 32];
  __shared__ alignas(16) bf16_t Bs[2 * 128 * 32];
  const int K = 128, N = D_;
  const int tid = threadIdx.x;
  const int lane = tid & 63;
  const int w = tid >> 6;
  const int wr = w >> 1, wc = w & 1;
  const int m0 = xcd_swz(blockIdx.x, gridDim.x) * 128;
  const int n0 = blockIdx.y * 128;

  f32x4 acc[4][4] = {};
  const bf16_t* ga = A  + (size_t)(m0 + (tid >> 2)) * K + (tid & 3) * 8;
  const bf16_t* gb = Wt + (size_t)(n0 + (tid >> 2)) * K + (tid & 3) * 8;
  const int kb = (lane >> 4) * 8;
  const int ar  = ((wr * 64 + (lane & 15)) << 5) + kb;
  const int br2 = ((wc * 64 + (lane & 15)) << 5) + kb;

  gemm_loop_db(ga, gb, As, Bs, K, (size_t)64 * K, ar, br2, tid, acc);

  const float sgf = 1.0f / (1.0f + __expf(-gate_ffn[0]));
  const int row0 = m0 + wr * 64 + ((lane >> 4) << 2);
  const int col0 = n0 + wc * 64 + (lane & 15);
#pragma unroll
  for (int j = 0; j < 4; ++j) {
    const int cc = col0 + j * 16;
    const f32x4 b2v = { b2[0 * D_ + cc], b2[1 * D_ + cc], b2[2 * D_ + cc], b2[3 * D_ + cc] };
#pragma unroll
    for (int i = 0; i < 4; ++i) {
      const int rr = row0 + i * 16;
#pragma unroll
      for (int r = 0; r < 4; ++r) {
        const f32x4 pr = *(const f32x4*)&probs[(size_t)(rr + r) * 4];
        const float bsum = pr[0]*b2v[0] + pr[1]*b2v[1] + pr[2]*b2v[2] + pr[3]*b2v[3];
        out[(size_t)(rr + r) * N + cc] =
            kv[(size_t)(rr + r) * N + cc] + sgf * (acc[i][j][r] + bsum);
      }
    }
  }
}

// ---------------------------------------------------------------------------
// MFMA flash attention, two segments, no-max exp2 softmax, swapped QK^T.
// Block = 128 thr (2 waves) = (b, h, 64 q-rows); each wave 32 rows via two
// Q-frag sets. Grid 1024 -> 4 independent blocks/CU (LDS 40KB).
// ---------------------------------------------------------------------------
__global__ __launch_bounds__(128, 2)
void attn_mfma_kernel(const bf16_t* __restrict__ qp, const bf16_t* __restrict__ kb,
                      const bf16_t* __restrict__ vt, bf16_t* __restrict__ attno,
                      const float* __restrict__ log_temp, const int* __restrict__ n_act) {
  __shared__ alignas(16) bf16_t Ks[2][64 * 64];
  __shared__ alignas(16) bf16_t Vs[2][64 * 64];
  __shared__ alignas(16) bf16_t Ps[2][32 * 64];

  const int dd = blockIdx.x;
  const int xcd = dd & 7, within = dd >> 3;       // 8 q-tiles per (b,h) share XCD
  const int qt = within & 7, slot0 = within >> 3;
  const int bh = slot0 * 8 + xcd;
  const int b = bh >> 4, h = bh & 15;

  const int tid = threadIdx.x;
  const int lane = tid & 63;
  const int w = tid >> 6;                          // 0..1
  const int lane15 = lane & 15, lgrp = lane >> 4, l7 = lane & 7;
  const int Na = n_act[0];
  float temp = __expf(log_temp[0]);
  temp = fminf(fmaxf(temp, 0.1f), 10.0f);
  const float lsc = LOG2E / (64.0f * temp);
  const int rowbase = qt * 64 + w * 32;

  // Two Q B-frag sets, pre-scaled
  const bf16_t* qsrcA = qp + (size_t)(b * TQ_ + rowbase + lane15) * D_ + h * 64 + lgrp * 8;
  const bf16_t* qsrcB = qsrcA + (size_t)16 * D_;
  bf16x8 qfA0 = *(const bf16x8*)qsrcA;
  bf16x8 qfA1 = *(const bf16x8*)(qsrcA + 32);
  bf16x8 qfB0 = *(const bf16x8*)qsrcB;
  bf16x8 qfB1 = *(const bf16x8*)(qsrcB + 32);
#pragma unroll
  for (int j = 0; j < 8; ++j) {
    qfA0[j] = (bf16_t)((float)qfA0[j] * lsc);
    qfA1[j] = (bf16_t)((float)qfA1[j] * lsc);
    qfB0[j] = (bf16_t)((float)qfB0[j] * lsc);
    qfB1[j] = (bf16_t)((float)qfB1[j] * lsc);
  }

  // staging: 128 thr x 16B = 2KB = 16 rows/issue; 4 issues per 64x64 tile.
  const int srow = tid >> 3;                       // 0..15
  const int schunk = (tid & 7) ^ (srow & 7);       // (srow+16k)&7 == srow&7
  const bf16_t* ksrc = kb + (size_t)(b * TK_ + srow) * D_ + h * 64 + schunk * 8;
  const bf16_t* vsrc = vt + ((size_t)(b * 16 + h) * 64 + srow) * TK_ + schunk * 8;

  f32x4 oA[4] = {}, oB[4] = {}, outA[4] = {}, outB[4] = {};
  float laccA = 0.f, laccB = 0.f;

  const float inv_sa = rsqrtf((float)(Na > 1 ? Na : 1));
  const int Ni = TK_ - Na;
  const float inv_si = rsqrtf((float)(Ni > 1 ? Ni : 1));

#pragma unroll
  for (int r = 0; r < 4; ++r) {
    gld_lds16(ksrc + (size_t)r * 16 * D_, &Ks[0][r * 1024 + tid * 8]);
    gld_lds16(vsrc + (size_t)r * 16 * TK_, &Vs[0][r * 1024 + tid * 8]);
  }

  for (int t = 0; t < TK_ / 64; ++t) {
    const int cur = t & 1;
    __syncthreads();
    if (t + 1 < TK_ / 64) {
      const int nb = cur ^ 1;
      const bf16_t* kN = ksrc + (size_t)(t + 1) * 64 * D_;
      const bf16_t* vN = vsrc + (size_t)(t + 1) * 64;
#pragma unroll
      for (int r = 0; r < 4; ++r) {
        gld_lds16(kN + (size_t)r * 16 * D_, &Ks[nb][r * 1024 + tid * 8]);
        gld_lds16(vN + (size_t)r * 16 * TK_, &Vs[nb][r * 1024 + tid * 8]);
      }
    }

    // ---- S^T = K @ Q for both sets (K frags shared) ----
    f32x4 sA[4], sB[4];
    __builtin_amdgcn_s_setprio(1);
#pragma unroll
    for (int cf = 0; cf < 4; ++cf) {
      const int krow = (cf * 16 + lane15) * 64;
      const bf16x8 kf0 = *(const bf16x8*)&Ks[cur][krow + ((lgrp ^ l7) << 3)];
      const bf16x8 kf1 = *(const bf16x8*)&Ks[cur][krow + (((lgrp + 4) ^ l7) << 3)];
      f32x4 s = {};
      s = __builtin_amdgcn_mfma_f32_16x16x32_bf16(kf0, qfA0, s, 0, 0, 0);
      s = __builtin_amdgcn_mfma_f32_16x16x32_bf16(kf1, qfA1, s, 0, 0, 0);
      sA[cf] = s;
      f32x4 s2 = {};
      s2 = __builtin_amdgcn_mfma_f32_16x16x32_bf16(kf0, qfB0, s2, 0, 0, 0);
      s2 = __builtin_amdgcn_mfma_f32_16x16x32_bf16(kf1, qfB1, s2, 0, 0, 0);
      sB[cf] = s2;
    }
    __builtin_amdgcn_s_setprio(0);

    // ---- p = exp2(s); lane-local l; packed bf16x4 P stores ----
#pragma unroll
    for (int cf = 0; cf < 4; ++cf) {
      const int c = cf * 2 + (lgrp >> 1);
      const int pcol = ((c ^ l7) << 3) + (lgrp & 1) * 4;
      f32x4 pA, pB;
#pragma unroll
      for (int r = 0; r < 4; ++r) pA[r] = exp2f(sA[cf][r]);
#pragma unroll
      for (int r = 0; r < 4; ++r) pB[r] = exp2f(sB[cf][r]);
      laccA += (pA[0] + pA[1]) + (pA[2] + pA[3]);
      laccB += (pB[0] + pB[1]) + (pB[2] + pB[3]);
      bf16x4 pvA, pvB;
#pragma unroll
      for (int r = 0; r < 4; ++r) { pvA[r] = (bf16_t)pA[r]; pvB[r] = (bf16_t)pB[r]; }
      *(bf16x4*)&Ps[w][lane15 * 64 + pcol]        = pvA;
      *(bf16x4*)&Ps[w][(16 + lane15) * 64 + pcol] = pvB;
    }

    // ---- O += P @ V for both sets (V frags shared) ----
    {
      const int prowA = lane15 * 64;
      const int prowB = (16 + lane15) * 64;
      const bf16x8 paA0 = *(const bf16x8*)&Ps[w][prowA + ((lgrp ^ l7) << 3)];
      const bf16x8 paA1 = *(const bf16x8*)&Ps[w][prowA + (((lgrp + 4) ^ l7) << 3)];
      const bf16x8 paB0 = *(const bf16x8*)&Ps[w][prowB + ((lgrp ^ l7) << 3)];
      const bf16x8 paB1 = *(const bf16x8*)&Ps[w][prowB + (((lgrp + 4) ^ l7) << 3)];
      __builtin_amdgcn_s_setprio(1);
#pragma unroll
      for (int df = 0; df < 4; ++df) {
        const int vrow = (df * 16 + lane15) * 64;
        const bf16x8 vf0 = *(const bf16x8*)&Vs[cur][vrow + ((lgrp ^ l7) << 3)];
        const bf16x8 vf1 = *(const bf16x8*)&Vs[cur][vrow + (((lgrp + 4) ^ l7) << 3)];
        oA[df] = __builtin_amdgcn_mfma_f32_16x16x32_bf16(paA0, vf0, oA[df], 0, 0, 0);
        oA[df] = __builtin_amdgcn_mfma_f32_16x16x32_bf16(paA1, vf1, oA[df], 0, 0, 0);
        oB[df] = __builtin_amdgcn_mfma_f32_16x16x32_bf16(paB0, vf0, oB[df], 0, 0, 0);
        oB[df] = __builtin_amdgcn_mfma_f32_16x16x32_bf16(paB1, vf1, oB[df], 0, 0, 0);
      }
      __builtin_amdgcn_s_setprio(0);
    }

    // ---- segment finalize ----
    const bool endA = ((t + 1) * 64 == Na);
    const bool endI = (t == TK_ / 64 - 1);
    if (endA || endI) {
      float lA = laccA, lB = laccB;
      lA += __shfl_xor(lA, 16); lA += __shfl_xor(lA, 32);
      lB += __shfl_xor(lB, 16); lB += __shfl_xor(lB, 32);
      const float ssc = endA ? inv_sa : -inv_si;
      f32x4 ivA, ivB;
#pragma unroll
      for (int r = 0; r < 4; ++r) {
        ivA[r] = ssc / __shfl(lA, lgrp * 4 + r);
        ivB[r] = ssc / __shfl(lB, lgrp * 4 + r);
      }
#pragma unroll
      for (int df = 0; df < 4; ++df) {
        outA[df] += oA[df] * ivA; oA[df] = (f32x4){};
        outB[df] += oB[df] * ivB; oB[df] = (f32x4){};
      }
      laccA = 0.f; laccB = 0.f;
    }
  }

#pragma unroll
  for (int df = 0; df < 4; ++df)
#pragma unroll
    for (int r = 0; r < 4; ++r) {
      const size_t ro = (size_t)(b * TQ_ + rowbase + lgrp * 4 + r) * D_ + h * 64 + df * 16 + lane15;
      attno[ro]           = (bf16_t)outA[df][r];
      attno[ro + 16 * D_] = (bf16_t)outB[df][r];
    }
}

// ---------------------------------------------------------------------------
// delta = rmsnorm(proj, dn_w); q_new = q + sigmoid(gate_attn)*delta (fp32 out)
// ---------------------------------------------------------------------------
__global__ __launch_bounds__(256)
void delta_qnew_kernel(const bf16_t* __restrict__ proj, const float* __restrict__ dn_w,
                       const float* __restrict__ q, const float* __restrict__ gate_attn,
                       float* __restrict__ qnew) {
  __shared__ float red[4];
  const int row = blockIdx.x;
  const int tid = threadIdx.x;
  bf16x4 pv = *(const bf16x4*)(proj + (size_t)row * D_ + tid * 4);
  f32x4 v;
#pragma unroll
  for (int c = 0; c < 4; ++c) v[c] = (float)pv[c];
  float ss = v[0]*v[0] + v[1]*v[1] + v[2]*v[2] + v[3]*v[3];
  ss = block_rsum(ss, red);
  const float rs = rsqrtf(ss * (1.0f / D_) + EPSF);
  const float sga = 1.0f / (1.0f + __expf(-gate_attn[0]));
  const int d = tid * 4;
  f32x4 wv = *(const f32x4*)(dn_w + d);
  f32x4 qv = *(const f32x4*)(q + (size_t)row * D_ + d);
  f32x4 out;
#pragma unroll
  for (int c = 0; c < 4; ++c) out[c] = qv[c] + sga * (v[c] * rs * wv[c]);
  *(f32x4*)&qnew[(size_t)row * D_ + d] = out;
}

// ---------------------------------------------------------------------------
extern "C" void kernel_launch(void* const* d_in, const int* in_sizes, int n_in,
                              void* d_out, int out_size, void* d_ws, size_t ws_size,
                              hipStream_t stream) {
  const float* q           = (const float*)d_in[0];
  const float* kv          = (const float*)d_in[1];
  const float* qn_w        = (const float*)d_in[2];
  const float* kva_w       = (const float*)d_in[3];
  const float* kvi_w       = (const float*)d_in[4];
  const float* dn_w        = (const float*)d_in[5];
  const float* fn_w        = (const float*)d_in[6];
  const float* Wq          = (const float*)d_in[7];
  const float* bq          = (const float*)d_in[8];
  const float* Wk          = (const float*)d_in[9];
  const float* bk          = (const float*)d_in[10];
  const float* Wv          = (const float*)d_in[11];
  const float* bv          = (const float*)d_in[12];
  const float* Wo          = (const float*)d_in[13];
  const float* bo          = (const float*)d_in[14];
  const float* active_bias = (const float*)d_in[15];
  const float* inactive_b  = (const float*)d_in[16];
  const float* log_temp    = (const float*)d_in[17];
  const float* gate_attn   = (const float*)d_in[18];
  const float* gate_ffn    = (const float*)d_in[19];
  const float* Wr          = (const float*)d_in[20];
  const float* br          = (const float*)d_in[21];
  const float* W1          = (const float*)d_in[22];
  const float* b1          = (const float*)d_in[23];
  const float* W2          = (const float*)d_in[24];
  const float* b2          = (const float*)d_in[25];
  const int*   n_act       = (const int*)d_in[27];

  char* ws = (char*)d_ws;
  size_t off = 0;
  auto alloc = [&](size_t bytes) -> char* {
    char* p = ws + off;
    off = (off + bytes + 255) & ~(size_t)255;
    return p;
  };

  bf16_t* wqT  = (bf16_t*)alloc((size_t)D_ * D_ * 2);
  bf16_t* wkT  = (bf16_t*)alloc((size_t)D_ * D_ * 2);   // frag-ordered
  bf16_t* wvT  = (bf16_t*)alloc((size_t)D_ * D_ * 2);   // frag-ordered
  bf16_t* woT  = (bf16_t*)alloc((size_t)D_ * D_ * 2);
  bf16_t* w1T  = (bf16_t*)alloc((size_t)256 * D_ * 2);
  bf16_t* w2T  = (bf16_t*)alloc((size_t)D_ * 128 * 2);
  bf16_t* kvb  = (bf16_t*)alloc((size_t)B_ * TK_ * D_ * 2);  // frag-ordered
  bf16_t* xn   = (bf16_t*)alloc((size_t)B_ * TK_ * D_ * 2);
  bf16_t* qn   = (bf16_t*)alloc((size_t)B_ * TQ_ * D_ * 2);
  bf16_t* qp   = (bf16_t*)alloc((size_t)B_ * TQ_ * D_ * 2);
  bf16_t* kbuf = (bf16_t*)alloc((size_t)B_ * TK_ * D_ * 2);
  bf16_t* vt   = (bf16_t*)alloc((size_t)B_ * D_ * TK_ * 2);
  float*  probs = (float*)alloc((size_t)B_ * TK_ * NE_ * 4);
  bf16_t* attno = qn;    // qn consumed by qp GEMM before attention writes
  bf16_t* proj  = qp;    // qp consumed by attention before proj GEMM writes
  bf16_t* a2buf = kbuf;  // kbuf consumed by attention before h-act writes
  (void)ws_size; (void)in_sizes; (void)n_in; (void)out_size;

  float* q_new_out  = (float*)d_out;
  float* kv_new_out = (float*)d_out + (size_t)B_ * TQ_ * D_;

  dim3 tb(32, 8);
  TP2 tpa; tpa.in[0] = Wq; tpa.in[1] = Wo; tpa.out[0] = wqT; tpa.out[1] = woT;
  transpose_conv2_kernel<<<dim3(32, 32, 2), tb, 0, stream>>>(tpa);
  TP2 tpf; tpf.in[0] = Wk; tpf.in[1] = Wv; tpf.out[0] = wkT; tpf.out[1] = wvT;
  transpose_fragorder_kernel<<<dim3(32, 32, 2), tb, 0, stream>>>(tpf);
  transpose_conv_kernel<<<dim3(2, 32, 4), tb, 0, stream>>>(W1, w1T, D_, 64, D_ * 64, D_, 64, 0);
  transpose_conv_kernel<<<dim3(32, 1, 4), tb, 0, stream>>>(W2, w2T, 32, D_, 32 * D_, 128, 0, 32);

  rms_kv_kernel<<<B_ * TK_, 256, 0, stream>>>(kv, kva_w, kvi_w, fn_w, active_bias,
                                              inactive_b, n_act, Wr, br, kvb, xn, probs);
  rms_q_kernel<<<B_ * TQ_, 256, 0, stream>>>(q, qn_w, qn);

  gemm64_tn<1><<<dim3(B_ * TQ_ / 64, D_ / 128), 256, 0, stream>>>(qn, wqT, bq, qp, B_ * TQ_, D_, D_);
  // fused K + V(transposed) projections, depth-2 counted-vmcnt pipeline
  gemm_kv<<<B_ * TK_ / 128 * (D_ / 128), 256, 0, stream>>>(kvb, wkT, wvT, bk, bv, kbuf, vt);

  attn_mfma_kernel<<<B_ * H_ * (TQ_ / 64), 128, 0, stream>>>(qp, kbuf, vt, attno, log_temp, n_act);

  gemm64_tn<1><<<dim3(B_ * TQ_ / 64, D_ / 128), 256, 0, stream>>>(attno, woT, bo, proj, B_ * TQ_, D_, D_);
  delta_qnew_kernel<<<B_ * TQ_, 256, 0, stream>>>(proj, dn_w, q, gate_attn, q_new_out);

  gemm64_h_act<<<dim3(B_ * TK_ / 64, 2), 256, 0, stream>>>(xn, w1T, b1, probs, a2buf);
  gemm_moe_kvnew<<<dim3(B_ * TK_ / 128, D_ / 128), 256, 0, stream>>>(a2buf, w2T, kv, probs, b2,
                                                                     gate_ffn, kv_new_out);
}